// Round 8
// baseline (390.643 us; speedup 1.0000x reference)
//
#include <hip/hip_runtime.h>
#include <math.h>

#define N_NODES 50000
#define N_EDGES 800000
#define HID 256
#define OUT_C 128
#define NEG_SLOPE 0.2f
#define SCAN_NB ((N_NODES + 255) / 256)   // 196

typedef __attribute__((ext_vector_type(8))) short bf16x8;   // 8 bf16 (4 VGPRs)
typedef __attribute__((ext_vector_type(4))) float f32x4;    // MFMA C/D
typedef _Float16 half_t;
typedef __attribute__((ext_vector_type(4))) _Float16 half4;
typedef __attribute__((ext_vector_type(2))) _Float16 half2t;

__device__ inline unsigned short bf16_rne(float x) {
    unsigned u = __float_as_uint(x);
    return (unsigned short)((u + 0x7fffu + ((u >> 16) & 1u)) >> 16);
}

// async global->LDS, 16B per lane (wave-uniform LDS base + lane*16 by HW)
__device__ __forceinline__ void async_copy16(const void* g, void* l) {
    __builtin_amdgcn_global_load_lds(
        (const __attribute__((address_space(1))) unsigned int*)g,
        (__attribute__((address_space(3))) unsigned int*)l, 16, 0, 0);
}

// ---------------- CSR build: hist (+rank), scan ----------------

__global__ __launch_bounds__(256) void hist_rank_kernel(
    const int* __restrict__ dst, int* __restrict__ counts, int* __restrict__ rank) {
    int e = blockIdx.x * 256 + threadIdx.x;
    if (e < N_EDGES) rank[e] = atomicAdd(&counts[dst[e]], 1);
}

__global__ __launch_bounds__(256) void block_scan_kernel(
    const int* __restrict__ counts, int* __restrict__ excl,
    int* __restrict__ blockSums, int n) {
    __shared__ int waveSums[4];
    int i = blockIdx.x * 256 + threadIdx.x;
    int lane = threadIdx.x & 63;
    int wv = threadIdx.x >> 6;
    int c = (i < n) ? counts[i] : 0;
    int v = c;
    #pragma unroll
    for (int off = 1; off < 64; off <<= 1) {
        int t = __shfl_up(v, off);
        if (lane >= off) v += t;
    }
    if (lane == 63) waveSums[wv] = v;
    __syncthreads();
    int waveOff = 0;
    #pragma unroll
    for (int w = 0; w < 4; w++)
        if (w < wv) waveOff += waveSums[w];
    if (i < n) excl[i] = waveOff + v - c;
    if (threadIdx.x == 255) blockSums[blockIdx.x] = waveOff + v;
}

__global__ __launch_bounds__(256) void add_offsets_kernel(
    int* __restrict__ excl, const int* __restrict__ blockSums, int n) {
    __shared__ int lds[4];
    int tid = threadIdx.x;
    int partial = 0;
    for (int j = tid; j < (int)blockIdx.x; j += 256) partial += blockSums[j];
    #pragma unroll
    for (int off = 32; off > 0; off >>= 1) partial += __shfl_down(partial, off);
    if ((tid & 63) == 0) lds[tid >> 6] = partial;
    __syncthreads();
    int prefix = lds[0] + lds[1] + lds[2] + lds[3];
    int i = blockIdx.x * 256 + tid;
    if (i < n) excl[i] += prefix;
    if (i == 0) excl[n] = N_EDGES;
}

// ---------------- prep: scatter (CSR) + pack W (+inline v) in one launch ----------------
// Two independent jobs merged to cut a dispatch gap. Pack's last-tile threads
// compute v[k] = dot(W[k,:], att) inline (only lanes m<2; ~2us) -- removes the
// separate compute_v launch + its dependency gap.

#define PACK1_T (8 * 17 * 64)   // 8704
#define PACK2_T (8 * 9 * 64)    // 4608
#define EDGE_BLOCKS ((N_EDGES + 255) / 256)          // 3125
#define PACK_BLOCKS ((PACK1_T + PACK2_T + 255) / 256) // 52

__global__ __launch_bounds__(256) void prep_kernel(
    const int* __restrict__ src, const int* __restrict__ dst,
    const int* __restrict__ offsets, const int* __restrict__ rank,
    int* __restrict__ src_sorted,
    const float* __restrict__ W1s, const float* __restrict__ att1s,
    const float* __restrict__ W1d, const float* __restrict__ att1d,
    const float* __restrict__ W2s, const float* __restrict__ att2s,
    const float* __restrict__ W2d, const float* __restrict__ att2d,
    unsigned short* __restrict__ hi1, unsigned short* __restrict__ lo1,
    unsigned short* __restrict__ hi2, unsigned short* __restrict__ lo2) {
    if (blockIdx.x < EDGE_BLOCKS) {
        int e = blockIdx.x * 256 + threadIdx.x;
        if (e < N_EDGES)
            src_sorted[offsets[dst[e]] + rank[e]] = src[e];
        return;
    }
    int t = (blockIdx.x - EDGE_BLOCKS) * 256 + threadIdx.x;
    const float *W, *Ws, *Wd, *avs, *avd; unsigned short *hi, *lo; int cout, NTL, tt;
    if (t < PACK1_T) {
        tt = t; W = W1s; Ws = W1s; Wd = W1d; avs = att1s; avd = att1d;
        hi = hi1; lo = lo1; cout = HID; NTL = 17;
    } else if (t < PACK1_T + PACK2_T) {
        tt = t - PACK1_T; W = W2s; Ws = W2s; Wd = W2d; avs = att2s; avd = att2d;
        hi = hi2; lo = lo2; cout = OUT_C; NTL = 9;
    } else return;
    int lane = tt & 63;
    int tile = (tt >> 6) % NTL;
    int ks = tt / (64 * NTL);
    int m = lane & 15;
    int kbase = ks * 32 + (lane >> 4) * 8;
    #pragma unroll
    for (int j = 0; j < 8; j++) {
        float val;
        if (tile < NTL - 1) {
            val = W[(size_t)(kbase + j) * cout + tile * 16 + m];
        } else if (m < 2) {
            const float* Wr = ((m == 0) ? Ws : Wd) + (size_t)(kbase + j) * cout;
            const float* av = (m == 0) ? avs : avd;
            float s = 0.f;
            for (int jj = 0; jj < cout; jj += 4) {
                float4 w4 = *(const float4*)(Wr + jj);
                float4 a4 = *(const float4*)(av + jj);
                s += w4.x * a4.x + w4.y * a4.y + w4.z * a4.z + w4.w * a4.w;
            }
            val = s;
        } else val = 0.f;
        unsigned short h = bf16_rne(val);
        hi[tt * 8 + j] = h;
        lo[tt * 8 + j] = bf16_rne(val - __uint_as_float((unsigned)h << 16));
    }
}

// ---------------- MFMA GEMM (+ logits): single pass, 2-phase dbuf LDS B ----------------
// r7 staged B in LDS but (a) GEMM1 ran 2 grid-y passes re-reading A (2x51MB) and
// (b) stage->drain->compute exposed the full load latency per ks. Now: one pass
// covering all NT=COUT/16+1 tiles (acc 136 VGPR for C=256), and T3-minimum
// 2-phase prefetch: issue ks+1 stage into the other buffer BEFORE computing ks,
// so the vmcnt drain at the barrier lands after ~100 MFMAs of cover.

template <int COUT>
__global__ __launch_bounds__(256) void mfma_gemm_kernel(
    const float* __restrict__ A, const unsigned short* __restrict__ Bhi,
    const unsigned short* __restrict__ Blo, half_t* __restrict__ H,
    float* __restrict__ a_s, float* __restrict__ a_d, int M) {
    constexpr int NT = COUT / 16 + 1;       // == NTL (W tiles + a-tile)
    __shared__ short sBh[2 * NT * 512];     // 17KB/buf (C=256)
    __shared__ short sBl[2 * NT * 512];
    int wave = threadIdx.x >> 6, lane = threadIdx.x & 63;
    int m = lane & 15, quad = lane >> 4;
    int row0 = blockIdx.x * 128 + wave * 32;
    f32x4 acc[2][NT];
    #pragma unroll
    for (int rg = 0; rg < 2; rg++)
        #pragma unroll
        for (int nt = 0; nt < NT; nt++)
            acc[rg][nt] = (f32x4){0.f, 0.f, 0.f, 0.f};

    const float* arow[2];
    #pragma unroll
    for (int rg = 0; rg < 2; rg++) {
        int r = row0 + rg * 16 + m;
        if (r >= M) r = M - 1;              // clamp: pad rows never stored
        arow[rg] = A + (size_t)r * HID;
    }

    // stage K-slice ks into buffer b (hi+lo: 2*NT 1KB units, round-robin waves)
    auto STAGE = [&](int ks, int b) {
        for (int u = wave; u < 2 * NT; u += 4) {
            int nt = (u < NT) ? u : u - NT;
            size_t goff = ((size_t)(ks * NT + nt) * 64 + lane) * 8;
            if (u < NT) async_copy16(Bhi + goff, sBh + b * NT * 512 + nt * 512);
            else        async_copy16(Blo + goff, sBl + b * NT * 512 + nt * 512);
        }
    };

    STAGE(0, 0);
    __syncthreads();                         // drain prologue stage
    int cur = 0;
    for (int ks = 0; ks < 8; ks++) {
        if (ks < 7) STAGE(ks + 1, cur ^ 1);  // prefetch overlaps compute below

        bf16x8 ah[2], al[2];
        #pragma unroll
        for (int rg = 0; rg < 2; rg++) {
            const float* ap = arow[rg] + ks * 32 + quad * 8;
            float4 v0 = *(const float4*)ap;
            float4 v1 = *(const float4*)(ap + 4);
            float av[8] = {v0.x, v0.y, v0.z, v0.w, v1.x, v1.y, v1.z, v1.w};
            #pragma unroll
            for (int j = 0; j < 8; j++) {
                unsigned short h = bf16_rne(av[j]);
                float hf = __uint_as_float((unsigned)h << 16);
                ah[rg][j] = (short)h;
                al[rg][j] = (short)bf16_rne(av[j] - hf);
            }
        }
        #pragma unroll
        for (int nt = 0; nt < NT; nt++) {
            bf16x8 bh = *(const bf16x8*)(sBh + cur * NT * 512 + nt * 512 + lane * 8);
            bf16x8 bl = *(const bf16x8*)(sBl + cur * NT * 512 + nt * 512 + lane * 8);
            acc[0][nt] = __builtin_amdgcn_mfma_f32_16x16x32_bf16(ah[0], bh, acc[0][nt], 0, 0, 0);
            acc[1][nt] = __builtin_amdgcn_mfma_f32_16x16x32_bf16(ah[1], bh, acc[1][nt], 0, 0, 0);
            acc[0][nt] = __builtin_amdgcn_mfma_f32_16x16x32_bf16(ah[0], bl, acc[0][nt], 0, 0, 0);
            acc[1][nt] = __builtin_amdgcn_mfma_f32_16x16x32_bf16(ah[1], bl, acc[1][nt], 0, 0, 0);
            acc[0][nt] = __builtin_amdgcn_mfma_f32_16x16x32_bf16(al[0], bh, acc[0][nt], 0, 0, 0);
            acc[1][nt] = __builtin_amdgcn_mfma_f32_16x16x32_bf16(al[1], bh, acc[1][nt], 0, 0, 0);
        }
        __syncthreads();                     // read-safety + drains prefetch
        cur ^= 1;
    }
    // C/D layout: col = lane&15, row = quad*4 + reg  [m89-verified]
    #pragma unroll
    for (int rg = 0; rg < 2; rg++)
        #pragma unroll
        for (int nt = 0; nt < NT - 1; nt++)
            #pragma unroll
            for (int r = 0; r < 4; r++) {
                int row = row0 + rg * 16 + quad * 4 + r;
                if (row < M)
                    H[(size_t)row * COUT + nt * 16 + m] = (half_t)acc[rg][nt][r];
            }
    #pragma unroll
    for (int rg = 0; rg < 2; rg++)
        #pragma unroll
        for (int r = 0; r < 4; r++) {
            int row = row0 + rg * 16 + quad * 4 + r;
            if (row < M) {
                if (m == 0) a_s[row] = acc[rg][NT - 1][r];
                else if (m == 1) a_d[row] = acc[rg][NT - 1][r];
            }
        }
}

// ---------------- fused aggregation: one wave per dst node (r7 form, at ceiling) ----------------

template <int C, bool RELU>
__global__ __launch_bounds__(256) void fused_aggregate_kernel(
    const int* __restrict__ offsets, const int* __restrict__ src_sorted,
    const float* __restrict__ a_src, const float* __restrict__ a_dst,
    const half_t* __restrict__ h, const float* __restrict__ bias,
    float* __restrict__ out) {
    constexpr int CH = 8;
    int node = (int)((blockIdx.x * 256u + threadIdx.x) >> 6);
    int lane = threadIdx.x & 63;
    if (node >= N_NODES) return;
    int beg = offsets[node], end = offsets[node + 1];
    float ad = a_dst[node];
    float s = 0.f;

    if (C == 256) {
        float4 acc = make_float4(0.f, 0.f, 0.f, 0.f);
        for (int base = beg; base < end; base += CH) {
            int cnt = end - base; if (cnt > CH) cnt = CH;
            int idx[CH];
            #pragma unroll
            for (int j = 0; j < CH; j++)
                idx[j] = src_sorted[(j < cnt) ? base + j : base];
            half4 hv[CH];
            #pragma unroll
            for (int j = 0; j < CH; j++)   // 8 independent 512B row gathers in flight
                hv[j] = *(const half4*)(h + ((unsigned)idx[j] * C + lane * 4));
            float w[CH];
            #pragma unroll
            for (int j = 0; j < CH; j++) {
                float l = a_src[idx[j]] + ad;
                l = fmaxf(l, l * NEG_SLOPE);
                w[j] = (j < cnt) ? __expf(l) : 0.f;
                s += w[j];
            }
            #pragma unroll
            for (int j = 0; j < CH; j++) {
                acc.x += w[j] * (float)hv[j][0]; acc.y += w[j] * (float)hv[j][1];
                acc.z += w[j] * (float)hv[j][2]; acc.w += w[j] * (float)hv[j][3];
            }
        }
        float inv = 1.f / (s + 1e-16f);
        float4 bv = *(const float4*)(bias + lane * 4);
        acc.x = acc.x * inv + bv.x; acc.y = acc.y * inv + bv.y;
        acc.z = acc.z * inv + bv.z; acc.w = acc.w * inv + bv.w;
        if (RELU) {
            acc.x = fmaxf(acc.x, 0.f); acc.y = fmaxf(acc.y, 0.f);
            acc.z = fmaxf(acc.z, 0.f); acc.w = fmaxf(acc.w, 0.f);
        }
        *(float4*)(out + (size_t)node * C + lane * 4) = acc;
    } else {
        float2 acc = make_float2(0.f, 0.f);
        for (int base = beg; base < end; base += CH) {
            int cnt = end - base; if (cnt > CH) cnt = CH;
            int idx[CH];
            #pragma unroll
            for (int j = 0; j < CH; j++)
                idx[j] = src_sorted[(j < cnt) ? base + j : base];
            half2t hv[CH];
            #pragma unroll
            for (int j = 0; j < CH; j++)
                hv[j] = *(const half2t*)(h + ((unsigned)idx[j] * C + lane * 2));
            float w[CH];
            #pragma unroll
            for (int j = 0; j < CH; j++) {
                float l = a_src[idx[j]] + ad;
                l = fmaxf(l, l * NEG_SLOPE);
                w[j] = (j < cnt) ? __expf(l) : 0.f;
                s += w[j];
            }
            #pragma unroll
            for (int j = 0; j < CH; j++) {
                acc.x += w[j] * (float)hv[j][0]; acc.y += w[j] * (float)hv[j][1];
            }
        }
        float inv = 1.f / (s + 1e-16f);
        float2 bv = *(const float2*)(bias + lane * 2);
        acc.x = acc.x * inv + bv.x; acc.y = acc.y * inv + bv.y;
        if (RELU) { acc.x = fmaxf(acc.x, 0.f); acc.y = fmaxf(acc.y, 0.f); }
        *(float2*)(out + (size_t)node * C + lane * 2) = acc;
    }
}

extern "C" void kernel_launch(void* const* d_in, const int* in_sizes, int n_in,
                              void* d_out, int out_size, void* d_ws, size_t ws_size,
                              hipStream_t stream) {
    const float* x     = (const float*)d_in[0];
    const int*   edge  = (const int*)d_in[1];
    const int*   src   = edge;
    const int*   dst   = edge + N_EDGES;
    const float* W1s   = (const float*)d_in[2];
    const float* W1d   = (const float*)d_in[3];
    const float* att1s = (const float*)d_in[4];
    const float* att1d = (const float*)d_in[5];
    const float* b1    = (const float*)d_in[6];
    const float* W2s   = (const float*)d_in[7];
    const float* W2d   = (const float*)d_in[8];
    const float* att2s = (const float*)d_in[9];
    const float* att2d = (const float*)d_in[10];
    const float* b2    = (const float*)d_in[11];
    float* out = (float*)d_out;

    // -------- workspace layout --------
    float* ws    = (float*)d_ws;
    half_t* h1   = (half_t*)ws;                        // N*256 halves (region N*256 floats)
    float* act2  = ws + (size_t)N_NODES * HID;         // N*256 fp32
    float* a_s   = act2 + (size_t)N_NODES * HID;       // N
    float* a_d   = a_s + N_NODES;                      // N
    int* ibase      = (int*)(a_d + N_NODES);
    int* src_sorted = ibase;                           // E
    int* rank       = src_sorted + N_EDGES;            // E
    int* counts     = rank + N_EDGES;                  // N
    int* offsets    = counts + N_NODES;                // N+1
    int* blockSums  = offsets + N_NODES + 1;           // SCAN_NB
    unsigned short* wp1h = (unsigned short*)(((uintptr_t)(blockSums + SCAN_NB) + 15) & ~(uintptr_t)15);
    unsigned short* wp1l = wp1h + PACK1_T * 8;
    unsigned short* wp2h = wp1l + PACK1_T * 8;
    unsigned short* wp2l = wp2h + PACK2_T * 8;
    half_t* h2 = h1;

    const int waveBlocksN = (N_NODES + 3) / 4;
    const int gemmBlocks = (N_NODES + 127) / 128;      // 391

    // -------- CSR build (atomic only in hist; scatter is rank-addressed) --------
    hipMemsetAsync(counts, 0, N_NODES * sizeof(int), stream);
    hist_rank_kernel<<<EDGE_BLOCKS, 256, 0, stream>>>(dst, counts, rank);
    block_scan_kernel<<<SCAN_NB, 256, 0, stream>>>(counts, offsets, blockSums, N_NODES);
    add_offsets_kernel<<<SCAN_NB, 256, 0, stream>>>(offsets, blockSums, N_NODES);

    // -------- scatter + pack (+inline v), one launch --------
    prep_kernel<<<EDGE_BLOCKS + PACK_BLOCKS, 256, 0, stream>>>(
        src, dst, offsets, rank, src_sorted,
        W1s, att1s, W1d, att1d, W2s, att2s, W2d, att2d,
        wp1h, wp1l, wp2h, wp2l);

    // -------- layer 1 --------
    mfma_gemm_kernel<HID><<<gemmBlocks, 256, 0, stream>>>(
        x, wp1h, wp1l, h1, a_s, a_d, N_NODES);
    fused_aggregate_kernel<HID, true><<<waveBlocksN, 256, 0, stream>>>(
        offsets, src_sorted, a_s, a_d, h1, b1, act2);

    // -------- layer 2 --------
    mfma_gemm_kernel<OUT_C><<<gemmBlocks, 256, 0, stream>>>(
        act2, wp2h, wp2l, h2, a_s, a_d, N_NODES);
    fused_aggregate_kernel<OUT_C, false><<<waveBlocksN, 256, 0, stream>>>(
        offsets, src_sorted, a_s, a_d, h2, b2, out);
}

// Round 9
// 340.856 us; speedup vs baseline: 1.1461x; 1.1461x over previous
//
#include <hip/hip_runtime.h>
#include <math.h>

#define N_NODES 50000
#define N_EDGES 800000
#define HID 256
#define OUT_C 128
#define NEG_SLOPE 0.2f
#define SCAN_NB ((N_NODES + 255) / 256)   // 196

typedef __attribute__((ext_vector_type(8))) short bf16x8;   // 8 bf16 (4 VGPRs)
typedef __attribute__((ext_vector_type(4))) float f32x4;    // MFMA C/D
typedef _Float16 half_t;
typedef __attribute__((ext_vector_type(4))) _Float16 half4;
typedef __attribute__((ext_vector_type(2))) _Float16 half2t;

__device__ inline unsigned short bf16_rne(float x) {
    unsigned u = __float_as_uint(x);
    return (unsigned short)((u + 0x7fffu + ((u >> 16) & 1u)) >> 16);
}

// async global->LDS, 16B per lane (wave-uniform LDS base + lane*16 by HW)
__device__ __forceinline__ void async_copy16(const void* g, void* l) {
    __builtin_amdgcn_global_load_lds(
        (const __attribute__((address_space(1))) unsigned int*)g,
        (__attribute__((address_space(3))) unsigned int*)l, 16, 0, 0);
}

// ---------------- CSR build: hist (+rank), scan, scatter ----------------

__global__ __launch_bounds__(256) void hist_rank_kernel(
    const int* __restrict__ dst, int* __restrict__ counts, int* __restrict__ rank) {
    int e = blockIdx.x * 256 + threadIdx.x;
    if (e < N_EDGES) rank[e] = atomicAdd(&counts[dst[e]], 1);
}

__global__ __launch_bounds__(256) void block_scan_kernel(
    const int* __restrict__ counts, int* __restrict__ excl,
    int* __restrict__ blockSums, int n) {
    __shared__ int waveSums[4];
    int i = blockIdx.x * 256 + threadIdx.x;
    int lane = threadIdx.x & 63;
    int wv = threadIdx.x >> 6;
    int c = (i < n) ? counts[i] : 0;
    int v = c;
    #pragma unroll
    for (int off = 1; off < 64; off <<= 1) {
        int t = __shfl_up(v, off);
        if (lane >= off) v += t;
    }
    if (lane == 63) waveSums[wv] = v;
    __syncthreads();
    int waveOff = 0;
    #pragma unroll
    for (int w = 0; w < 4; w++)
        if (w < wv) waveOff += waveSums[w];
    if (i < n) excl[i] = waveOff + v - c;
    if (threadIdx.x == 255) blockSums[blockIdx.x] = waveOff + v;
}

__global__ __launch_bounds__(256) void add_offsets_kernel(
    int* __restrict__ excl, const int* __restrict__ blockSums, int n) {
    __shared__ int lds[4];
    int tid = threadIdx.x;
    int partial = 0;
    for (int j = tid; j < (int)blockIdx.x; j += 256) partial += blockSums[j];
    #pragma unroll
    for (int off = 32; off > 0; off >>= 1) partial += __shfl_down(partial, off);
    if ((tid & 63) == 0) lds[tid >> 6] = partial;
    __syncthreads();
    int prefix = lds[0] + lds[1] + lds[2] + lds[3];
    int i = blockIdx.x * 256 + tid;
    if (i < n) excl[i] += prefix;
    if (i == 0) excl[n] = N_EDGES;
}

__global__ __launch_bounds__(256) void scatter_kernel(
    const int* __restrict__ src, const int* __restrict__ dst,
    const int* __restrict__ offsets, const int* __restrict__ rank,
    int* __restrict__ src_sorted) {
    int e = blockIdx.x * 256 + threadIdx.x;
    if (e >= N_EDGES) return;
    src_sorted[offsets[dst[e]] + rank[e]] = src[e];
}

// ---------------- v = W @ att for all 4 (layer,side) combos ----------------
// (r8 lesson: do NOT inline this as a serial per-lane loop in pack — the
// wave-parallel reduction here is latency-clean.)

__global__ __launch_bounds__(64) void compute_v_all_kernel(
    const float* __restrict__ W1s, const float* __restrict__ att1s,
    const float* __restrict__ W1d, const float* __restrict__ att1d,
    const float* __restrict__ W2s, const float* __restrict__ att2s,
    const float* __restrict__ W2d, const float* __restrict__ att2d,
    float* __restrict__ v1s, float* __restrict__ v1d,
    float* __restrict__ v2s, float* __restrict__ v2d) {
    int k = blockIdx.x;
    int lane = threadIdx.x;
    const float* W; const float* att; float* v; int cout;
    switch (blockIdx.y) {
        case 0: W = W1s; att = att1s; v = v1s; cout = HID; break;
        case 1: W = W1d; att = att1d; v = v1d; cout = HID; break;
        case 2: W = W2s; att = att2s; v = v2s; cout = OUT_C; break;
        default: W = W2d; att = att2d; v = v2d; cout = OUT_C; break;
    }
    float sum = 0.f;
    for (int j = lane; j < cout; j += 64)
        sum += W[k * cout + j] * att[j];
    #pragma unroll
    for (int off = 32; off > 0; off >>= 1)
        sum += __shfl_down(sum, off);
    if (lane == 0) v[k] = sum;
}

// ---------------- pack W (+v tile) into B-fragment layout, hi/lo bf16 ----------------

#define PACK1_T (8 * 17 * 64)   // 8704
#define PACK2_T (8 * 9 * 64)    // 4608

__global__ __launch_bounds__(256) void pack_all_kernel(
    const float* __restrict__ W1, const float* __restrict__ v1s, const float* __restrict__ v1d,
    const float* __restrict__ W2, const float* __restrict__ v2s, const float* __restrict__ v2d,
    unsigned short* __restrict__ hi1, unsigned short* __restrict__ lo1,
    unsigned short* __restrict__ hi2, unsigned short* __restrict__ lo2) {
    int t = blockIdx.x * 256 + threadIdx.x;
    const float *W, *vs, *vd; unsigned short *hi, *lo; int cout, NTL, tt;
    if (t < PACK1_T)            { tt = t;           W = W1; vs = v1s; vd = v1d; hi = hi1; lo = lo1; cout = HID;  NTL = 17; }
    else if (t < PACK1_T + PACK2_T) { tt = t - PACK1_T; W = W2; vs = v2s; vd = v2d; hi = hi2; lo = lo2; cout = OUT_C; NTL = 9; }
    else return;
    int lane = tt & 63;
    int tile = (tt >> 6) % NTL;
    int ks = tt / (64 * NTL);
    int m = lane & 15;
    int kbase = ks * 32 + (lane >> 4) * 8;
    #pragma unroll
    for (int j = 0; j < 8; j++) {
        float val;
        if (tile < NTL - 1) val = W[(kbase + j) * cout + tile * 16 + m];
        else val = (m == 0) ? vs[kbase + j] : (m == 1) ? vd[kbase + j] : 0.f;
        unsigned short h = bf16_rne(val);
        hi[tt * 8 + j] = h;
        lo[tt * 8 + j] = bf16_rne(val - __uint_as_float((unsigned)h << 16));
    }
}

// ---------------- MFMA GEMM (+ logits): single pass, 2-phase dbuf LDS B ----------------
// Single pass over A covering all NT=COUT/16+1 B-tiles (GEMM1 A traffic halved
// vs the r7 2-pass form), with T3-minimum 2-phase prefetch: stage ks+1 into the
// other LDS buffer before computing ks; the vmcnt drain at the barrier lands
// after ~NT*6 MFMAs of cover.

template <int COUT>
__global__ __launch_bounds__(256) void mfma_gemm_kernel(
    const float* __restrict__ A, const unsigned short* __restrict__ Bhi,
    const unsigned short* __restrict__ Blo, half_t* __restrict__ H,
    float* __restrict__ a_s, float* __restrict__ a_d, int M) {
    constexpr int NT = COUT / 16 + 1;       // == NTL (W tiles + a-tile)
    __shared__ short sBh[2 * NT * 512];     // 17KB/buf (C=256)
    __shared__ short sBl[2 * NT * 512];
    int wave = threadIdx.x >> 6, lane = threadIdx.x & 63;
    int m = lane & 15, quad = lane >> 4;
    int row0 = blockIdx.x * 128 + wave * 32;
    f32x4 acc[2][NT];
    #pragma unroll
    for (int rg = 0; rg < 2; rg++)
        #pragma unroll
        for (int nt = 0; nt < NT; nt++)
            acc[rg][nt] = (f32x4){0.f, 0.f, 0.f, 0.f};

    const float* arow[2];
    #pragma unroll
    for (int rg = 0; rg < 2; rg++) {
        int r = row0 + rg * 16 + m;
        if (r >= M) r = M - 1;              // clamp: pad rows never stored
        arow[rg] = A + (size_t)r * HID;
    }

    // stage K-slice ks into buffer b (hi+lo: 2*NT 1KB units, round-robin waves)
    auto STAGE = [&](int ks, int b) {
        for (int u = wave; u < 2 * NT; u += 4) {
            int nt = (u < NT) ? u : u - NT;
            size_t goff = ((size_t)(ks * NT + nt) * 64 + lane) * 8;
            if (u < NT) async_copy16(Bhi + goff, sBh + b * NT * 512 + nt * 512);
            else        async_copy16(Blo + goff, sBl + b * NT * 512 + nt * 512);
        }
    };

    STAGE(0, 0);
    __syncthreads();                         // drain prologue stage
    int cur = 0;
    for (int ks = 0; ks < 8; ks++) {
        if (ks < 7) STAGE(ks + 1, cur ^ 1);  // prefetch overlaps compute below

        bf16x8 ah[2], al[2];
        #pragma unroll
        for (int rg = 0; rg < 2; rg++) {
            const float* ap = arow[rg] + ks * 32 + quad * 8;
            float4 v0 = *(const float4*)ap;
            float4 v1 = *(const float4*)(ap + 4);
            float av[8] = {v0.x, v0.y, v0.z, v0.w, v1.x, v1.y, v1.z, v1.w};
            #pragma unroll
            for (int j = 0; j < 8; j++) {
                unsigned short h = bf16_rne(av[j]);
                float hf = __uint_as_float((unsigned)h << 16);
                ah[rg][j] = (short)h;
                al[rg][j] = (short)bf16_rne(av[j] - hf);
            }
        }
        #pragma unroll
        for (int nt = 0; nt < NT; nt++) {
            bf16x8 bh = *(const bf16x8*)(sBh + cur * NT * 512 + nt * 512 + lane * 8);
            bf16x8 bl = *(const bf16x8*)(sBl + cur * NT * 512 + nt * 512 + lane * 8);
            acc[0][nt] = __builtin_amdgcn_mfma_f32_16x16x32_bf16(ah[0], bh, acc[0][nt], 0, 0, 0);
            acc[1][nt] = __builtin_amdgcn_mfma_f32_16x16x32_bf16(ah[1], bh, acc[1][nt], 0, 0, 0);
            acc[0][nt] = __builtin_amdgcn_mfma_f32_16x16x32_bf16(ah[0], bl, acc[0][nt], 0, 0, 0);
            acc[1][nt] = __builtin_amdgcn_mfma_f32_16x16x32_bf16(ah[1], bl, acc[1][nt], 0, 0, 0);
            acc[0][nt] = __builtin_amdgcn_mfma_f32_16x16x32_bf16(al[0], bh, acc[0][nt], 0, 0, 0);
            acc[1][nt] = __builtin_amdgcn_mfma_f32_16x16x32_bf16(al[1], bh, acc[1][nt], 0, 0, 0);
        }
        __syncthreads();                     // read-safety + drains prefetch
        cur ^= 1;
    }
    // C/D layout: col = lane&15, row = quad*4 + reg  [m89-verified]
    #pragma unroll
    for (int rg = 0; rg < 2; rg++)
        #pragma unroll
        for (int nt = 0; nt < NT - 1; nt++)
            #pragma unroll
            for (int r = 0; r < 4; r++) {
                int row = row0 + rg * 16 + quad * 4 + r;
                if (row < M)
                    H[(size_t)row * COUT + nt * 16 + m] = (half_t)acc[rg][nt][r];
            }
    #pragma unroll
    for (int rg = 0; rg < 2; rg++)
        #pragma unroll
        for (int r = 0; r < 4; r++) {
            int row = row0 + rg * 16 + quad * 4 + r;
            if (row < M) {
                if (m == 0) a_s[row] = acc[rg][NT - 1][r];
                else if (m == 1) a_d[row] = acc[rg][NT - 1][r];
            }
        }
}

// ---------------- fused aggregation: one wave per dst node (r7 form, at ceiling) ----------------

template <int C, bool RELU>
__global__ __launch_bounds__(256) void fused_aggregate_kernel(
    const int* __restrict__ offsets, const int* __restrict__ src_sorted,
    const float* __restrict__ a_src, const float* __restrict__ a_dst,
    const half_t* __restrict__ h, const float* __restrict__ bias,
    float* __restrict__ out) {
    constexpr int CH = 8;
    int node = (int)((blockIdx.x * 256u + threadIdx.x) >> 6);
    int lane = threadIdx.x & 63;
    if (node >= N_NODES) return;
    int beg = offsets[node], end = offsets[node + 1];
    float ad = a_dst[node];
    float s = 0.f;

    if (C == 256) {
        float4 acc = make_float4(0.f, 0.f, 0.f, 0.f);
        for (int base = beg; base < end; base += CH) {
            int cnt = end - base; if (cnt > CH) cnt = CH;
            int idx[CH];
            #pragma unroll
            for (int j = 0; j < CH; j++)
                idx[j] = src_sorted[(j < cnt) ? base + j : base];
            half4 hv[CH];
            #pragma unroll
            for (int j = 0; j < CH; j++)   // 8 independent 512B row gathers in flight
                hv[j] = *(const half4*)(h + ((unsigned)idx[j] * C + lane * 4));
            float w[CH];
            #pragma unroll
            for (int j = 0; j < CH; j++) {
                float l = a_src[idx[j]] + ad;
                l = fmaxf(l, l * NEG_SLOPE);
                w[j] = (j < cnt) ? __expf(l) : 0.f;
                s += w[j];
            }
            #pragma unroll
            for (int j = 0; j < CH; j++) {
                acc.x += w[j] * (float)hv[j][0]; acc.y += w[j] * (float)hv[j][1];
                acc.z += w[j] * (float)hv[j][2]; acc.w += w[j] * (float)hv[j][3];
            }
        }
        float inv = 1.f / (s + 1e-16f);
        float4 bv = *(const float4*)(bias + lane * 4);
        acc.x = acc.x * inv + bv.x; acc.y = acc.y * inv + bv.y;
        acc.z = acc.z * inv + bv.z; acc.w = acc.w * inv + bv.w;
        if (RELU) {
            acc.x = fmaxf(acc.x, 0.f); acc.y = fmaxf(acc.y, 0.f);
            acc.z = fmaxf(acc.z, 0.f); acc.w = fmaxf(acc.w, 0.f);
        }
        *(float4*)(out + (size_t)node * C + lane * 4) = acc;
    } else {
        float2 acc = make_float2(0.f, 0.f);
        for (int base = beg; base < end; base += CH) {
            int cnt = end - base; if (cnt > CH) cnt = CH;
            int idx[CH];
            #pragma unroll
            for (int j = 0; j < CH; j++)
                idx[j] = src_sorted[(j < cnt) ? base + j : base];
            half2t hv[CH];
            #pragma unroll
            for (int j = 0; j < CH; j++)
                hv[j] = *(const half2t*)(h + ((unsigned)idx[j] * C + lane * 2));
            float w[CH];
            #pragma unroll
            for (int j = 0; j < CH; j++) {
                float l = a_src[idx[j]] + ad;
                l = fmaxf(l, l * NEG_SLOPE);
                w[j] = (j < cnt) ? __expf(l) : 0.f;
                s += w[j];
            }
            #pragma unroll
            for (int j = 0; j < CH; j++) {
                acc.x += w[j] * (float)hv[j][0]; acc.y += w[j] * (float)hv[j][1];
            }
        }
        float inv = 1.f / (s + 1e-16f);
        float2 bv = *(const float2*)(bias + lane * 2);
        acc.x = acc.x * inv + bv.x; acc.y = acc.y * inv + bv.y;
        if (RELU) { acc.x = fmaxf(acc.x, 0.f); acc.y = fmaxf(acc.y, 0.f); }
        *(float2*)(out + (size_t)node * C + lane * 2) = acc;
    }
}

extern "C" void kernel_launch(void* const* d_in, const int* in_sizes, int n_in,
                              void* d_out, int out_size, void* d_ws, size_t ws_size,
                              hipStream_t stream) {
    const float* x     = (const float*)d_in[0];
    const int*   edge  = (const int*)d_in[1];
    const int*   src   = edge;
    const int*   dst   = edge + N_EDGES;
    const float* W1s   = (const float*)d_in[2];
    const float* W1d   = (const float*)d_in[3];
    const float* att1s = (const float*)d_in[4];
    const float* att1d = (const float*)d_in[5];
    const float* b1    = (const float*)d_in[6];
    const float* W2s   = (const float*)d_in[7];
    const float* W2d   = (const float*)d_in[8];
    const float* att2s = (const float*)d_in[9];
    const float* att2d = (const float*)d_in[10];
    const float* b2    = (const float*)d_in[11];
    float* out = (float*)d_out;

    // -------- workspace layout (r7 form) --------
    float* ws    = (float*)d_ws;
    half_t* h1   = (half_t*)ws;                        // N*256 halves (region N*256 floats)
    float* act2  = ws + (size_t)N_NODES * HID;         // N*256 fp32
    float* a_s   = act2 + (size_t)N_NODES * HID;       // N
    float* a_d   = a_s + N_NODES;                      // N
    float* vbuf  = a_d + N_NODES;                      // 4*256
    int* ibase      = (int*)(vbuf + 4 * HID);
    int* src_sorted = ibase;                           // E
    int* rank       = src_sorted + N_EDGES;            // E
    int* counts     = rank + N_EDGES;                  // N
    int* offsets    = counts + N_NODES;                // N+1
    int* blockSums  = offsets + N_NODES + 1;           // SCAN_NB
    unsigned short* wp1h = (unsigned short*)(((uintptr_t)(blockSums + SCAN_NB) + 15) & ~(uintptr_t)15);
    unsigned short* wp1l = wp1h + PACK1_T * 8;
    unsigned short* wp2h = wp1l + PACK1_T * 8;
    unsigned short* wp2l = wp2h + PACK2_T * 8;
    float* v1s = vbuf, *v1d = vbuf + HID, *v2s = vbuf + 2 * HID, *v2d = vbuf + 3 * HID;
    half_t* h2 = h1;

    const int edgeBlocks = (N_EDGES + 255) / 256;
    const int waveBlocksN = (N_NODES + 3) / 4;
    const int gemmBlocks = (N_NODES + 127) / 128;      // 391

    // -------- CSR build (atomic only in hist; scatter is rank-addressed) --------
    hipMemsetAsync(counts, 0, N_NODES * sizeof(int), stream);
    hist_rank_kernel<<<edgeBlocks, 256, 0, stream>>>(dst, counts, rank);
    block_scan_kernel<<<SCAN_NB, 256, 0, stream>>>(counts, offsets, blockSums, N_NODES);
    add_offsets_kernel<<<SCAN_NB, 256, 0, stream>>>(offsets, blockSums, N_NODES);
    scatter_kernel<<<edgeBlocks, 256, 0, stream>>>(src, dst, offsets, rank, src_sorted);

    // -------- v vectors + packed B (both layers) --------
    compute_v_all_kernel<<<dim3(HID, 4), 64, 0, stream>>>(
        W1s, att1s, W1d, att1d, W2s, att2s, W2d, att2d, v1s, v1d, v2s, v2d);
    pack_all_kernel<<<(PACK1_T + PACK2_T + 255) / 256, 256, 0, stream>>>(
        W1s, v1s, v1d, W2s, v2s, v2d, wp1h, wp1l, wp2h, wp2l);

    // -------- layer 1 --------
    mfma_gemm_kernel<HID><<<gemmBlocks, 256, 0, stream>>>(
        x, wp1h, wp1l, h1, a_s, a_d, N_NODES);
    fused_aggregate_kernel<HID, true><<<waveBlocksN, 256, 0, stream>>>(
        offsets, src_sorted, a_s, a_d, h1, b1, act2);

    // -------- layer 2 --------
    mfma_gemm_kernel<OUT_C><<<gemmBlocks, 256, 0, stream>>>(
        act2, wp2h, wp2l, h2, a_s, a_d, N_NODES);
    fused_aggregate_kernel<OUT_C, false><<<waveBlocksN, 256, 0, stream>>>(
        offsets, src_sorted, a_s, a_d, h2, b2, out);
}

// Round 10
// 323.665 us; speedup vs baseline: 1.2069x; 1.0531x over previous
//
#include <hip/hip_runtime.h>
#include <math.h>

#define N_NODES 50000
#define N_EDGES 800000
#define HID 256
#define OUT_C 128
#define NEG_SLOPE 0.2f
#define SCAN_NB ((N_NODES + 255) / 256)   // 196

typedef __attribute__((ext_vector_type(8))) short bf16x8;   // 8 bf16 (4 VGPRs)
typedef __attribute__((ext_vector_type(4))) float f32x4;    // MFMA C/D
typedef _Float16 half_t;
typedef __attribute__((ext_vector_type(4))) _Float16 half4;
typedef __attribute__((ext_vector_type(2))) _Float16 half2t;

__device__ inline unsigned short bf16_rne(float x) {
    unsigned u = __float_as_uint(x);
    return (unsigned short)((u + 0x7fffu + ((u >> 16) & 1u)) >> 16);
}

// async global->LDS, 16B per lane (wave-uniform LDS base + lane*16 by HW)
__device__ __forceinline__ void async_copy16(const void* g, void* l) {
    __builtin_amdgcn_global_load_lds(
        (const __attribute__((address_space(1))) unsigned int*)g,
        (__attribute__((address_space(3))) unsigned int*)l, 16, 0, 0);
}

// ---------------- CSR build: hist (+rank), scan, scatter ----------------

__global__ __launch_bounds__(256) void hist_rank_kernel(
    const int* __restrict__ dst, int* __restrict__ counts, int* __restrict__ rank) {
    int e = blockIdx.x * 256 + threadIdx.x;
    if (e < N_EDGES) rank[e] = atomicAdd(&counts[dst[e]], 1);
}

__global__ __launch_bounds__(256) void block_scan_kernel(
    const int* __restrict__ counts, int* __restrict__ excl,
    int* __restrict__ blockSums, int n) {
    __shared__ int waveSums[4];
    int i = blockIdx.x * 256 + threadIdx.x;
    int lane = threadIdx.x & 63;
    int wv = threadIdx.x >> 6;
    int c = (i < n) ? counts[i] : 0;
    int v = c;
    #pragma unroll
    for (int off = 1; off < 64; off <<= 1) {
        int t = __shfl_up(v, off);
        if (lane >= off) v += t;
    }
    if (lane == 63) waveSums[wv] = v;
    __syncthreads();
    int waveOff = 0;
    #pragma unroll
    for (int w = 0; w < 4; w++)
        if (w < wv) waveOff += waveSums[w];
    if (i < n) excl[i] = waveOff + v - c;
    if (threadIdx.x == 255) blockSums[blockIdx.x] = waveOff + v;
}

__global__ __launch_bounds__(256) void add_offsets_kernel(
    int* __restrict__ excl, const int* __restrict__ blockSums, int n) {
    __shared__ int lds[4];
    int tid = threadIdx.x;
    int partial = 0;
    for (int j = tid; j < (int)blockIdx.x; j += 256) partial += blockSums[j];
    #pragma unroll
    for (int off = 32; off > 0; off >>= 1) partial += __shfl_down(partial, off);
    if ((tid & 63) == 0) lds[tid >> 6] = partial;
    __syncthreads();
    int prefix = lds[0] + lds[1] + lds[2] + lds[3];
    int i = blockIdx.x * 256 + tid;
    if (i < n) excl[i] += prefix;
    if (i == 0) excl[n] = N_EDGES;
}

__global__ __launch_bounds__(256) void scatter_kernel(
    const int* __restrict__ src, const int* __restrict__ dst,
    const int* __restrict__ offsets, const int* __restrict__ rank,
    int* __restrict__ src_sorted) {
    int e = blockIdx.x * 256 + threadIdx.x;
    if (e >= N_EDGES) return;
    src_sorted[offsets[dst[e]] + rank[e]] = src[e];
}

// ---------------- v = W @ att for all 4 (layer,side) combos ----------------

__global__ __launch_bounds__(64) void compute_v_all_kernel(
    const float* __restrict__ W1s, const float* __restrict__ att1s,
    const float* __restrict__ W1d, const float* __restrict__ att1d,
    const float* __restrict__ W2s, const float* __restrict__ att2s,
    const float* __restrict__ W2d, const float* __restrict__ att2d,
    float* __restrict__ v1s, float* __restrict__ v1d,
    float* __restrict__ v2s, float* __restrict__ v2d) {
    int k = blockIdx.x;
    int lane = threadIdx.x;
    const float* W; const float* att; float* v; int cout;
    switch (blockIdx.y) {
        case 0: W = W1s; att = att1s; v = v1s; cout = HID; break;
        case 1: W = W1d; att = att1d; v = v1d; cout = HID; break;
        case 2: W = W2s; att = att2s; v = v2s; cout = OUT_C; break;
        default: W = W2d; att = att2d; v = v2d; cout = OUT_C; break;
    }
    float sum = 0.f;
    for (int j = lane; j < cout; j += 64)
        sum += W[k * cout + j] * att[j];
    #pragma unroll
    for (int off = 32; off > 0; off >>= 1)
        sum += __shfl_down(sum, off);
    if (lane == 0) v[k] = sum;
}

// ---------------- pack W (+v tile) into B-fragment layout, hi/lo bf16 ----------------

#define PACK1_T (8 * 17 * 64)   // 8704
#define PACK2_T (8 * 9 * 64)    // 4608

__global__ __launch_bounds__(256) void pack_all_kernel(
    const float* __restrict__ W1, const float* __restrict__ v1s, const float* __restrict__ v1d,
    const float* __restrict__ W2, const float* __restrict__ v2s, const float* __restrict__ v2d,
    unsigned short* __restrict__ hi1, unsigned short* __restrict__ lo1,
    unsigned short* __restrict__ hi2, unsigned short* __restrict__ lo2) {
    int t = blockIdx.x * 256 + threadIdx.x;
    const float *W, *vs, *vd; unsigned short *hi, *lo; int cout, NTL, tt;
    if (t < PACK1_T)            { tt = t;           W = W1; vs = v1s; vd = v1d; hi = hi1; lo = lo1; cout = HID;  NTL = 17; }
    else if (t < PACK1_T + PACK2_T) { tt = t - PACK1_T; W = W2; vs = v2s; vd = v2d; hi = hi2; lo = lo2; cout = OUT_C; NTL = 9; }
    else return;
    int lane = tt & 63;
    int tile = (tt >> 6) % NTL;
    int ks = tt / (64 * NTL);
    int m = lane & 15;
    int kbase = ks * 32 + (lane >> 4) * 8;
    #pragma unroll
    for (int j = 0; j < 8; j++) {
        float val;
        if (tile < NTL - 1) val = W[(kbase + j) * cout + tile * 16 + m];
        else val = (m == 0) ? vs[kbase + j] : (m == 1) ? vd[kbase + j] : 0.f;
        unsigned short h = bf16_rne(val);
        hi[tt * 8 + j] = h;
        lo[tt * 8 + j] = bf16_rne(val - __uint_as_float((unsigned)h << 16));
    }
}

// ---------------- MFMA GEMM (+ logits): 2-pass, 2-phase dbuf LDS B ----------------
// r9 lesson: the binding resource is resident waves/CU (grid x LDS/block), not
// traffic. This is r7's proven geometry (grid 782, NT=9/8, 128 rows/block) with
// r9's pipeline: double-buffered LDS (36KB -> 4 blocks/CU) and stage(ks+1)
// issued before compute(ks) so the vmcnt drain at the barrier is covered by
// ~54 MFMAs and by the ~3 co-resident blocks.

template <int COUT, int NT, bool WRITE_A>
__device__ __forceinline__ void gemm_body(
    const float* __restrict__ A, const unsigned short* __restrict__ Bhi,
    const unsigned short* __restrict__ Blo, half_t* __restrict__ H,
    float* __restrict__ a_s, float* __restrict__ a_d, int M, int tile0,
    short* sBh, short* sBl) {
    const int NTL = COUT / 16 + 1;
    int wave = threadIdx.x >> 6, lane = threadIdx.x & 63;
    int m = lane & 15, quad = lane >> 4;
    int row0 = blockIdx.x * 128 + wave * 32;
    f32x4 acc[2][NT];
    #pragma unroll
    for (int rg = 0; rg < 2; rg++)
        #pragma unroll
        for (int nt = 0; nt < NT; nt++)
            acc[rg][nt] = (f32x4){0.f, 0.f, 0.f, 0.f};

    const float* arow[2];
    #pragma unroll
    for (int rg = 0; rg < 2; rg++) {
        int r = row0 + rg * 16 + m;
        if (r >= M) r = M - 1;          // clamp: pad rows never stored
        arow[rg] = A + (size_t)r * HID;
    }

    // stage K-slice ks into buffer b (hi+lo: 2*NT 1KB units, round-robin waves)
    auto STAGE = [&](int ks, int b) {
        for (int u = wave; u < 2 * NT; u += 4) {
            int nt = (u < NT) ? u : u - NT;
            int tile = (WRITE_A && nt == NT - 1) ? (COUT / 16) : (tile0 + nt);
            size_t goff = ((size_t)(ks * NTL + tile) * 64 + lane) * 8;
            if (u < NT) async_copy16(Bhi + goff, sBh + b * NT * 512 + nt * 512);
            else        async_copy16(Blo + goff, sBl + b * NT * 512 + nt * 512);
        }
    };

    STAGE(0, 0);
    __syncthreads();                     // drain prologue stage
    int cur = 0;
    for (int ks = 0; ks < 8; ks++) {
        if (ks < 7) STAGE(ks + 1, cur ^ 1);  // prefetch overlaps compute below

        bf16x8 ah[2], al[2];
        #pragma unroll
        for (int rg = 0; rg < 2; rg++) {
            const float* ap = arow[rg] + ks * 32 + quad * 8;
            float4 v0 = *(const float4*)ap;
            float4 v1 = *(const float4*)(ap + 4);
            float av[8] = {v0.x, v0.y, v0.z, v0.w, v1.x, v1.y, v1.z, v1.w};
            #pragma unroll
            for (int j = 0; j < 8; j++) {
                unsigned short h = bf16_rne(av[j]);
                float hf = __uint_as_float((unsigned)h << 16);
                ah[rg][j] = (short)h;
                al[rg][j] = (short)bf16_rne(av[j] - hf);
            }
        }
        #pragma unroll
        for (int nt = 0; nt < NT; nt++) {
            bf16x8 bh = *(const bf16x8*)(sBh + cur * NT * 512 + nt * 512 + lane * 8);
            bf16x8 bl = *(const bf16x8*)(sBl + cur * NT * 512 + nt * 512 + lane * 8);
            acc[0][nt] = __builtin_amdgcn_mfma_f32_16x16x32_bf16(ah[0], bh, acc[0][nt], 0, 0, 0);
            acc[1][nt] = __builtin_amdgcn_mfma_f32_16x16x32_bf16(ah[1], bh, acc[1][nt], 0, 0, 0);
            acc[0][nt] = __builtin_amdgcn_mfma_f32_16x16x32_bf16(ah[0], bl, acc[0][nt], 0, 0, 0);
            acc[1][nt] = __builtin_amdgcn_mfma_f32_16x16x32_bf16(ah[1], bl, acc[1][nt], 0, 0, 0);
            acc[0][nt] = __builtin_amdgcn_mfma_f32_16x16x32_bf16(al[0], bh, acc[0][nt], 0, 0, 0);
            acc[1][nt] = __builtin_amdgcn_mfma_f32_16x16x32_bf16(al[1], bh, acc[1][nt], 0, 0, 0);
        }
        __syncthreads();                 // read-safety + drains prefetch
        cur ^= 1;
    }
    // C/D layout: col = lane&15, row = quad*4 + reg  [m89-verified]
    const int NW = WRITE_A ? NT - 1 : NT;
    #pragma unroll
    for (int rg = 0; rg < 2; rg++)
        #pragma unroll
        for (int nt = 0; nt < NW; nt++)
            #pragma unroll
            for (int r = 0; r < 4; r++) {
                int row = row0 + rg * 16 + quad * 4 + r;
                if (row < M)
                    H[(size_t)row * COUT + (tile0 + nt) * 16 + m] = (half_t)acc[rg][nt][r];
            }
    if (WRITE_A) {
        #pragma unroll
        for (int rg = 0; rg < 2; rg++)
            #pragma unroll
            for (int r = 0; r < 4; r++) {
                int row = row0 + rg * 16 + quad * 4 + r;
                if (row < M) {
                    if (m == 0) a_s[row] = acc[rg][NT - 1][r];
                    else if (m == 1) a_d[row] = acc[rg][NT - 1][r];
                }
            }
    }
}

template <int COUT>
__global__ __launch_bounds__(256) void mfma_gemm_a_kernel(
    const float* __restrict__ A, const unsigned short* __restrict__ Bhi,
    const unsigned short* __restrict__ Blo, half_t* __restrict__ H,
    float* __restrict__ a_s, float* __restrict__ a_d, int M) {
    __shared__ short sBh[2 * 9 * 512];   // 18KB (dbuf)
    __shared__ short sBl[2 * 9 * 512];   // 18KB (dbuf) -> 36KB total, 4 blocks/CU
    if (blockIdx.y == 0)
        gemm_body<COUT, 9, true>(A, Bhi, Blo, H, a_s, a_d, M, 0, sBh, sBl);
    else
        gemm_body<COUT, 8, false>(A, Bhi, Blo, H, a_s, a_d, M, 8, sBh, sBl);
}

// ---------------- fused aggregation: one wave per dst node (at fabric ceiling) ----------------

template <int C, bool RELU>
__global__ __launch_bounds__(256) void fused_aggregate_kernel(
    const int* __restrict__ offsets, const int* __restrict__ src_sorted,
    const float* __restrict__ a_src, const float* __restrict__ a_dst,
    const half_t* __restrict__ h, const float* __restrict__ bias,
    float* __restrict__ out) {
    constexpr int CH = 8;
    int node = (int)((blockIdx.x * 256u + threadIdx.x) >> 6);
    int lane = threadIdx.x & 63;
    if (node >= N_NODES) return;
    int beg = offsets[node], end = offsets[node + 1];
    float ad = a_dst[node];
    float s = 0.f;

    if (C == 256) {
        float4 acc = make_float4(0.f, 0.f, 0.f, 0.f);
        for (int base = beg; base < end; base += CH) {
            int cnt = end - base; if (cnt > CH) cnt = CH;
            int idx[CH];
            #pragma unroll
            for (int j = 0; j < CH; j++)
                idx[j] = src_sorted[(j < cnt) ? base + j : base];
            half4 hv[CH];
            #pragma unroll
            for (int j = 0; j < CH; j++)   // 8 independent 512B row gathers in flight
                hv[j] = *(const half4*)(h + ((unsigned)idx[j] * C + lane * 4));
            float w[CH];
            #pragma unroll
            for (int j = 0; j < CH; j++) {
                float l = a_src[idx[j]] + ad;
                l = fmaxf(l, l * NEG_SLOPE);
                w[j] = (j < cnt) ? __expf(l) : 0.f;
                s += w[j];
            }
            #pragma unroll
            for (int j = 0; j < CH; j++) {
                acc.x += w[j] * (float)hv[j][0]; acc.y += w[j] * (float)hv[j][1];
                acc.z += w[j] * (float)hv[j][2]; acc.w += w[j] * (float)hv[j][3];
            }
        }
        float inv = 1.f / (s + 1e-16f);
        float4 bv = *(const float4*)(bias + lane * 4);
        acc.x = acc.x * inv + bv.x; acc.y = acc.y * inv + bv.y;
        acc.z = acc.z * inv + bv.z; acc.w = acc.w * inv + bv.w;
        if (RELU) {
            acc.x = fmaxf(acc.x, 0.f); acc.y = fmaxf(acc.y, 0.f);
            acc.z = fmaxf(acc.z, 0.f); acc.w = fmaxf(acc.w, 0.f);
        }
        *(float4*)(out + (size_t)node * C + lane * 4) = acc;
    } else {
        float2 acc = make_float2(0.f, 0.f);
        for (int base = beg; base < end; base += CH) {
            int cnt = end - base; if (cnt > CH) cnt = CH;
            int idx[CH];
            #pragma unroll
            for (int j = 0; j < CH; j++)
                idx[j] = src_sorted[(j < cnt) ? base + j : base];
            half2t hv[CH];
            #pragma unroll
            for (int j = 0; j < CH; j++)
                hv[j] = *(const half2t*)(h + ((unsigned)idx[j] * C + lane * 2));
            float w[CH];
            #pragma unroll
            for (int j = 0; j < CH; j++) {
                float l = a_src[idx[j]] + ad;
                l = fmaxf(l, l * NEG_SLOPE);
                w[j] = (j < cnt) ? __expf(l) : 0.f;
                s += w[j];
            }
            #pragma unroll
            for (int j = 0; j < CH; j++) {
                acc.x += w[j] * (float)hv[j][0]; acc.y += w[j] * (float)hv[j][1];
            }
        }
        float inv = 1.f / (s + 1e-16f);
        float2 bv = *(const float2*)(bias + lane * 2);
        acc.x = acc.x * inv + bv.x; acc.y = acc.y * inv + bv.y;
        if (RELU) { acc.x = fmaxf(acc.x, 0.f); acc.y = fmaxf(acc.y, 0.f); }
        *(float2*)(out + (size_t)node * C + lane * 2) = acc;
    }
}

extern "C" void kernel_launch(void* const* d_in, const int* in_sizes, int n_in,
                              void* d_out, int out_size, void* d_ws, size_t ws_size,
                              hipStream_t stream) {
    const float* x     = (const float*)d_in[0];
    const int*   edge  = (const int*)d_in[1];
    const int*   src   = edge;
    const int*   dst   = edge + N_EDGES;
    const float* W1s   = (const float*)d_in[2];
    const float* W1d   = (const float*)d_in[3];
    const float* att1s = (const float*)d_in[4];
    const float* att1d = (const float*)d_in[5];
    const float* b1    = (const float*)d_in[6];
    const float* W2s   = (const float*)d_in[7];
    const float* W2d   = (const float*)d_in[8];
    const float* att2s = (const float*)d_in[9];
    const float* att2d = (const float*)d_in[10];
    const float* b2    = (const float*)d_in[11];
    float* out = (float*)d_out;

    // -------- workspace layout (r7 form) --------
    float* ws    = (float*)d_ws;
    half_t* h1   = (half_t*)ws;                        // N*256 halves (region N*256 floats)
    float* act2  = ws + (size_t)N_NODES * HID;         // N*256 fp32
    float* a_s   = act2 + (size_t)N_NODES * HID;       // N
    float* a_d   = a_s + N_NODES;                      // N
    float* vbuf  = a_d + N_NODES;                      // 4*256
    int* ibase      = (int*)(vbuf + 4 * HID);
    int* src_sorted = ibase;                           // E
    int* rank       = src_sorted + N_EDGES;            // E
    int* counts     = rank + N_EDGES;                  // N
    int* offsets    = counts + N_NODES;                // N+1
    int* blockSums  = offsets + N_NODES + 1;           // SCAN_NB
    unsigned short* wp1h = (unsigned short*)(((uintptr_t)(blockSums + SCAN_NB) + 15) & ~(uintptr_t)15);
    unsigned short* wp1l = wp1h + PACK1_T * 8;
    unsigned short* wp2h = wp1l + PACK1_T * 8;
    unsigned short* wp2l = wp2h + PACK2_T * 8;
    float* v1s = vbuf, *v1d = vbuf + HID, *v2s = vbuf + 2 * HID, *v2d = vbuf + 3 * HID;
    half_t* h2 = h1;

    const int edgeBlocks = (N_EDGES + 255) / 256;
    const int waveBlocksN = (N_NODES + 3) / 4;
    const int gemmBlocks = (N_NODES + 127) / 128;      // 391

    // -------- CSR build (atomic only in hist; scatter is rank-addressed) --------
    hipMemsetAsync(counts, 0, N_NODES * sizeof(int), stream);
    hist_rank_kernel<<<edgeBlocks, 256, 0, stream>>>(dst, counts, rank);
    block_scan_kernel<<<SCAN_NB, 256, 0, stream>>>(counts, offsets, blockSums, N_NODES);
    add_offsets_kernel<<<SCAN_NB, 256, 0, stream>>>(offsets, blockSums, N_NODES);
    scatter_kernel<<<edgeBlocks, 256, 0, stream>>>(src, dst, offsets, rank, src_sorted);

    // -------- v vectors + packed B (both layers) --------
    compute_v_all_kernel<<<dim3(HID, 4), 64, 0, stream>>>(
        W1s, att1s, W1d, att1d, W2s, att2s, W2d, att2d, v1s, v1d, v2s, v2d);
    pack_all_kernel<<<(PACK1_T + PACK2_T + 255) / 256, 256, 0, stream>>>(
        W1s, v1s, v1d, W2s, v2s, v2d, wp1h, wp1l, wp2h, wp2l);

    // -------- layer 1 --------
    mfma_gemm_a_kernel<HID><<<dim3(gemmBlocks, 2), 256, 0, stream>>>(
        x, wp1h, wp1l, h1, a_s, a_d, N_NODES);
    fused_aggregate_kernel<HID, true><<<waveBlocksN, 256, 0, stream>>>(
        offsets, src_sorted, a_s, a_d, h1, b1, act2);

    // -------- layer 2 --------
    mfma_gemm_a_kernel<OUT_C><<<dim3(gemmBlocks, 1), 256, 0, stream>>>(
        act2, wp2h, wp2l, h2, a_s, a_d, N_NODES);
    fused_aggregate_kernel<OUT_C, false><<<waveBlocksN, 256, 0, stream>>>(
        offsets, src_sorted, a_s, a_d, h2, b2, out);
}

// Round 13
// 319.489 us; speedup vs baseline: 1.2227x; 1.0131x over previous
//
#include <hip/hip_runtime.h>
#include <math.h>

#define N_NODES 50000
#define N_EDGES 800000
#define HID 256
#define OUT_C 128
#define NEG_SLOPE 0.2f
#define SCAN_NB ((N_NODES + 255) / 256)   // 196

typedef __attribute__((ext_vector_type(8))) short bf16x8;   // 8 bf16 (4 VGPRs)
typedef __attribute__((ext_vector_type(4))) float f32x4;    // MFMA C/D
typedef _Float16 half_t;
typedef __attribute__((ext_vector_type(4))) _Float16 half4;
typedef __attribute__((ext_vector_type(2))) _Float16 half2t;

__device__ inline unsigned short bf16_rne(float x) {
    unsigned u = __float_as_uint(x);
    return (unsigned short)((u + 0x7fffu + ((u >> 16) & 1u)) >> 16);
}

// async global->LDS, 16B per lane (wave-uniform LDS base + lane*16 by HW)
__device__ __forceinline__ void async_copy16(const void* g, void* l) {
    __builtin_amdgcn_global_load_lds(
        (const __attribute__((address_space(1))) unsigned int*)g,
        (__attribute__((address_space(3))) unsigned int*)l, 16, 0, 0);
}

// ---------------- CSR build: hist (+rank), scan, scatter ----------------

__global__ __launch_bounds__(256) void hist_rank_kernel(
    const int* __restrict__ dst, int* __restrict__ counts, int* __restrict__ rank) {
    int e = blockIdx.x * 256 + threadIdx.x;
    if (e < N_EDGES) rank[e] = atomicAdd(&counts[dst[e]], 1);
}

__global__ __launch_bounds__(256) void block_scan_kernel(
    const int* __restrict__ counts, int* __restrict__ excl,
    int* __restrict__ blockSums, int n) {
    __shared__ int waveSums[4];
    int i = blockIdx.x * 256 + threadIdx.x;
    int lane = threadIdx.x & 63;
    int wv = threadIdx.x >> 6;
    int c = (i < n) ? counts[i] : 0;
    int v = c;
    #pragma unroll
    for (int off = 1; off < 64; off <<= 1) {
        int t = __shfl_up(v, off);
        if (lane >= off) v += t;
    }
    if (lane == 63) waveSums[wv] = v;
    __syncthreads();
    int waveOff = 0;
    #pragma unroll
    for (int w = 0; w < 4; w++)
        if (w < wv) waveOff += waveSums[w];
    if (i < n) excl[i] = waveOff + v - c;
    if (threadIdx.x == 255) blockSums[blockIdx.x] = waveOff + v;
}

__global__ __launch_bounds__(256) void add_offsets_kernel(
    int* __restrict__ excl, const int* __restrict__ blockSums, int n) {
    __shared__ int lds[4];
    int tid = threadIdx.x;
    int partial = 0;
    for (int j = tid; j < (int)blockIdx.x; j += 256) partial += blockSums[j];
    #pragma unroll
    for (int off = 32; off > 0; off >>= 1) partial += __shfl_down(partial, off);
    if ((tid & 63) == 0) lds[tid >> 6] = partial;
    __syncthreads();
    int prefix = lds[0] + lds[1] + lds[2] + lds[3];
    int i = blockIdx.x * 256 + tid;
    if (i < n) excl[i] += prefix;
    if (i == 0) excl[n] = N_EDGES;
}

__global__ __launch_bounds__(256) void scatter_kernel(
    const int* __restrict__ src, const int* __restrict__ dst,
    const int* __restrict__ offsets, const int* __restrict__ rank,
    int* __restrict__ src_sorted) {
    int e = blockIdx.x * 256 + threadIdx.x;
    if (e >= N_EDGES) return;
    src_sorted[offsets[dst[e]] + rank[e]] = src[e];
}

// ---------------- v = W @ att for all 4 (layer,side) combos ----------------

__global__ __launch_bounds__(64) void compute_v_all_kernel(
    const float* __restrict__ W1s, const float* __restrict__ att1s,
    const float* __restrict__ W1d, const float* __restrict__ att1d,
    const float* __restrict__ W2s, const float* __restrict__ att2s,
    const float* __restrict__ W2d, const float* __restrict__ att2d,
    float* __restrict__ v1s, float* __restrict__ v1d,
    float* __restrict__ v2s, float* __restrict__ v2d) {
    int k = blockIdx.x;
    int lane = threadIdx.x;
    const float* W; const float* att; float* v; int cout;
    switch (blockIdx.y) {
        case 0: W = W1s; att = att1s; v = v1s; cout = HID; break;
        case 1: W = W1d; att = att1d; v = v1d; cout = HID; break;
        case 2: W = W2s; att = att2s; v = v2s; cout = OUT_C; break;
        default: W = W2d; att = att2d; v = v2d; cout = OUT_C; break;
    }
    float sum = 0.f;
    for (int j = lane; j < cout; j += 64)
        sum += W[k * cout + j] * att[j];
    #pragma unroll
    for (int off = 32; off > 0; off >>= 1)
        sum += __shfl_down(sum, off);
    if (lane == 0) v[k] = sum;
}

// ---------------- pack W (+v tile) into B-fragment layout, hi/lo bf16 ----------------

#define PACK1_T (8 * 17 * 64)   // 8704
#define PACK2_T (8 * 9 * 64)    // 4608

__global__ __launch_bounds__(256) void pack_all_kernel(
    const float* __restrict__ W1, const float* __restrict__ v1s, const float* __restrict__ v1d,
    const float* __restrict__ W2, const float* __restrict__ v2s, const float* __restrict__ v2d,
    unsigned short* __restrict__ hi1, unsigned short* __restrict__ lo1,
    unsigned short* __restrict__ hi2, unsigned short* __restrict__ lo2) {
    int t = blockIdx.x * 256 + threadIdx.x;
    const float *W, *vs, *vd; unsigned short *hi, *lo; int cout, NTL, tt;
    if (t < PACK1_T)            { tt = t;           W = W1; vs = v1s; vd = v1d; hi = hi1; lo = lo1; cout = HID;  NTL = 17; }
    else if (t < PACK1_T + PACK2_T) { tt = t - PACK1_T; W = W2; vs = v2s; vd = v2d; hi = hi2; lo = lo2; cout = OUT_C; NTL = 9; }
    else return;
    int lane = tt & 63;
    int tile = (tt >> 6) % NTL;
    int ks = tt / (64 * NTL);
    int m = lane & 15;
    int kbase = ks * 32 + (lane >> 4) * 8;
    #pragma unroll
    for (int j = 0; j < 8; j++) {
        float val;
        if (tile < NTL - 1) val = W[(kbase + j) * cout + tile * 16 + m];
        else val = (m == 0) ? vs[kbase + j] : (m == 1) ? vd[kbase + j] : 0.f;
        unsigned short h = bf16_rne(val);
        hi[tt * 8 + j] = h;
        lo[tt * 8 + j] = bf16_rne(val - __uint_as_float((unsigned)h << 16));
    }
}

// ---------------- MFMA GEMM (+ logits): 2-pass, dbuf LDS B ----------------
// r10-proven geometry (grid 782, NT=9/8, 128 rows/block, 36KB dbuf LDS).
// ASPLIT: layer 2 reads A as pre-split hi/lo bf16 (written by agg1's OSPLIT at
// zero extra traffic) -> the per-ks fp32->bf16 conversion VALU is gone there.

template <int COUT, int NT, bool WRITE_A, bool ASPLIT>
__device__ __forceinline__ void gemm_body(
    const float* __restrict__ A,
    const unsigned short* __restrict__ Ahi, const unsigned short* __restrict__ Alo,
    const unsigned short* __restrict__ Bhi, const unsigned short* __restrict__ Blo,
    half_t* __restrict__ H,
    float* __restrict__ a_s, float* __restrict__ a_d, int M, int tile0,
    short* sBh, short* sBl) {
    const int NTL = COUT / 16 + 1;
    int wave = threadIdx.x >> 6, lane = threadIdx.x & 63;
    int m = lane & 15, quad = lane >> 4;
    int row0 = blockIdx.x * 128 + wave * 32;
    f32x4 acc[2][NT];
    #pragma unroll
    for (int rg = 0; rg < 2; rg++)
        #pragma unroll
        for (int nt = 0; nt < NT; nt++)
            acc[rg][nt] = (f32x4){0.f, 0.f, 0.f, 0.f};

    const float* arow[2];
    const unsigned short* arh[2];
    const unsigned short* arl[2];
    #pragma unroll
    for (int rg = 0; rg < 2; rg++) {
        int r = row0 + rg * 16 + m;
        if (r >= M) r = M - 1;          // clamp: pad rows never stored
        if (ASPLIT) {
            arh[rg] = Ahi + (size_t)r * HID;
            arl[rg] = Alo + (size_t)r * HID;
        } else {
            arow[rg] = A + (size_t)r * HID;
        }
    }

    // stage K-slice ks into buffer b (hi+lo: 2*NT 1KB units, round-robin waves)
    auto STAGE = [&](int ks, int b) {
        for (int u = wave; u < 2 * NT; u += 4) {
            int nt = (u < NT) ? u : u - NT;
            int tile = (WRITE_A && nt == NT - 1) ? (COUT / 16) : (tile0 + nt);
            size_t goff = ((size_t)(ks * NTL + tile) * 64 + lane) * 8;
            if (u < NT) async_copy16(Bhi + goff, sBh + b * NT * 512 + nt * 512);
            else        async_copy16(Blo + goff, sBl + b * NT * 512 + nt * 512);
        }
    };

    STAGE(0, 0);
    __syncthreads();                     // drain prologue stage
    int cur = 0;
    for (int ks = 0; ks < 8; ks++) {
        if (ks < 7) STAGE(ks + 1, cur ^ 1);  // prefetch overlaps compute below

        bf16x8 ah[2], al[2];
        #pragma unroll
        for (int rg = 0; rg < 2; rg++) {
            if (ASPLIT) {
                ah[rg] = *(const bf16x8*)(arh[rg] + ks * 32 + quad * 8);
                al[rg] = *(const bf16x8*)(arl[rg] + ks * 32 + quad * 8);
            } else {
                const float* ap = arow[rg] + ks * 32 + quad * 8;
                float4 v0 = *(const float4*)ap;
                float4 v1 = *(const float4*)(ap + 4);
                float av[8] = {v0.x, v0.y, v0.z, v0.w, v1.x, v1.y, v1.z, v1.w};
                #pragma unroll
                for (int j = 0; j < 8; j++) {
                    unsigned short h = bf16_rne(av[j]);
                    float hf = __uint_as_float((unsigned)h << 16);
                    ah[rg][j] = (short)h;
                    al[rg][j] = (short)bf16_rne(av[j] - hf);
                }
            }
        }
        #pragma unroll
        for (int nt = 0; nt < NT; nt++) {
            bf16x8 bh = *(const bf16x8*)(sBh + cur * NT * 512 + nt * 512 + lane * 8);
            bf16x8 bl = *(const bf16x8*)(sBl + cur * NT * 512 + nt * 512 + lane * 8);
            acc[0][nt] = __builtin_amdgcn_mfma_f32_16x16x32_bf16(ah[0], bh, acc[0][nt], 0, 0, 0);
            acc[1][nt] = __builtin_amdgcn_mfma_f32_16x16x32_bf16(ah[1], bh, acc[1][nt], 0, 0, 0);
            acc[0][nt] = __builtin_amdgcn_mfma_f32_16x16x32_bf16(ah[0], bl, acc[0][nt], 0, 0, 0);
            acc[1][nt] = __builtin_amdgcn_mfma_f32_16x16x32_bf16(ah[1], bl, acc[1][nt], 0, 0, 0);
            acc[0][nt] = __builtin_amdgcn_mfma_f32_16x16x32_bf16(al[0], bh, acc[0][nt], 0, 0, 0);
            acc[1][nt] = __builtin_amdgcn_mfma_f32_16x16x32_bf16(al[1], bh, acc[1][nt], 0, 0, 0);
        }
        __syncthreads();                 // read-safety + drains prefetch
        cur ^= 1;
    }
    // C/D layout: col = lane&15, row = quad*4 + reg  [m89-verified]
    const int NW = WRITE_A ? NT - 1 : NT;
    #pragma unroll
    for (int rg = 0; rg < 2; rg++)
        #pragma unroll
        for (int nt = 0; nt < NW; nt++)
            #pragma unroll
            for (int r = 0; r < 4; r++) {
                int row = row0 + rg * 16 + quad * 4 + r;
                if (row < M)
                    H[(size_t)row * COUT + (tile0 + nt) * 16 + m] = (half_t)acc[rg][nt][r];
            }
    if (WRITE_A) {
        #pragma unroll
        for (int rg = 0; rg < 2; rg++)
            #pragma unroll
            for (int r = 0; r < 4; r++) {
                int row = row0 + rg * 16 + quad * 4 + r;
                if (row < M) {
                    if (m == 0) a_s[row] = acc[rg][NT - 1][r];
                    else if (m == 1) a_d[row] = acc[rg][NT - 1][r];
                }
            }
    }
}

template <int COUT, bool ASPLIT>
__global__ __launch_bounds__(256) void mfma_gemm_a_kernel(
    const float* __restrict__ A,
    const unsigned short* __restrict__ Ahi, const unsigned short* __restrict__ Alo,
    const unsigned short* __restrict__ Bhi, const unsigned short* __restrict__ Blo,
    half_t* __restrict__ H,
    float* __restrict__ a_s, float* __restrict__ a_d, int M) {
    __shared__ short sBh[2 * 9 * 512];   // 18KB (dbuf)
    __shared__ short sBl[2 * 9 * 512];   // 18KB (dbuf) -> 36KB total
    if (blockIdx.y == 0)
        gemm_body<COUT, 9, true, ASPLIT>(A, Ahi, Alo, Bhi, Blo, H, a_s, a_d, M, 0, sBh, sBl);
    else
        gemm_body<COUT, 8, false, ASPLIT>(A, Ahi, Alo, Bhi, Blo, H, a_s, a_d, M, 8, sBh, sBl);
}

// ---------------- fused aggregation: one wave per dst node (at fabric ceiling) ----------------
// OSPLIT: layer-1 writes act2 as hi/lo bf16 pairs (same byte count as fp32,
// same rounding GEMM2 would apply) so GEMM2 gets pre-split A for free.

template <int C, bool RELU, bool OSPLIT>
__global__ __launch_bounds__(256) void fused_aggregate_kernel(
    const int* __restrict__ offsets, const int* __restrict__ src_sorted,
    const float* __restrict__ a_src, const float* __restrict__ a_dst,
    const half_t* __restrict__ h, const float* __restrict__ bias,
    float* __restrict__ out,
    unsigned short* __restrict__ outhi, unsigned short* __restrict__ outlo) {
    constexpr int CH = 8;
    int node = (int)((blockIdx.x * 256u + threadIdx.x) >> 6);
    int lane = threadIdx.x & 63;
    if (node >= N_NODES) return;
    int beg = offsets[node], end = offsets[node + 1];
    float ad = a_dst[node];
    float s = 0.f;

    if (C == 256) {
        float4 acc = make_float4(0.f, 0.f, 0.f, 0.f);
        for (int base = beg; base < end; base += CH) {
            int cnt = end - base; if (cnt > CH) cnt = CH;
            int idx[CH];
            #pragma unroll
            for (int j = 0; j < CH; j++)
                idx[j] = src_sorted[(j < cnt) ? base + j : base];
            half4 hv[CH];
            #pragma unroll
            for (int j = 0; j < CH; j++)   // 8 independent 512B row gathers in flight
                hv[j] = *(const half4*)(h + ((unsigned)idx[j] * C + lane * 4));
            float w[CH];
            #pragma unroll
            for (int j = 0; j < CH; j++) {
                float l = a_src[idx[j]] + ad;
                l = fmaxf(l, l * NEG_SLOPE);
                w[j] = (j < cnt) ? __expf(l) : 0.f;
                s += w[j];
            }
            #pragma unroll
            for (int j = 0; j < CH; j++) {
                acc.x += w[j] * (float)hv[j][0]; acc.y += w[j] * (float)hv[j][1];
                acc.z += w[j] * (float)hv[j][2]; acc.w += w[j] * (float)hv[j][3];
            }
        }
        float inv = 1.f / (s + 1e-16f);
        float4 bv = *(const float4*)(bias + lane * 4);
        acc.x = acc.x * inv + bv.x; acc.y = acc.y * inv + bv.y;
        acc.z = acc.z * inv + bv.z; acc.w = acc.w * inv + bv.w;
        if (RELU) {
            acc.x = fmaxf(acc.x, 0.f); acc.y = fmaxf(acc.y, 0.f);
            acc.z = fmaxf(acc.z, 0.f); acc.w = fmaxf(acc.w, 0.f);
        }
        if (OSPLIT) {
            float o[4] = {acc.x, acc.y, acc.z, acc.w};
            ushort4 h4, l4;
            unsigned short* hp = (unsigned short*)&h4;
            unsigned short* lp = (unsigned short*)&l4;
            #pragma unroll
            for (int j = 0; j < 4; j++) {
                unsigned short hh = bf16_rne(o[j]);
                hp[j] = hh;
                lp[j] = bf16_rne(o[j] - __uint_as_float((unsigned)hh << 16));
            }
            *(ushort4*)(outhi + (size_t)node * C + lane * 4) = h4;
            *(ushort4*)(outlo + (size_t)node * C + lane * 4) = l4;
        } else {
            *(float4*)(out + (size_t)node * C + lane * 4) = acc;
        }
    } else {
        float2 acc = make_float2(0.f, 0.f);
        for (int base = beg; base < end; base += CH) {
            int cnt = end - base; if (cnt > CH) cnt = CH;
            int idx[CH];
            #pragma unroll
            for (int j = 0; j < CH; j++)
                idx[j] = src_sorted[(j < cnt) ? base + j : base];
            half2t hv[CH];
            #pragma unroll
            for (int j = 0; j < CH; j++)
                hv[j] = *(const half2t*)(h + ((unsigned)idx[j] * C + lane * 2));
            float w[CH];
            #pragma unroll
            for (int j = 0; j < CH; j++) {
                float l = a_src[idx[j]] + ad;
                l = fmaxf(l, l * NEG_SLOPE);
                w[j] = (j < cnt) ? __expf(l) : 0.f;
                s += w[j];
            }
            #pragma unroll
            for (int j = 0; j < CH; j++) {
                acc.x += w[j] * (float)hv[j][0]; acc.y += w[j] * (float)hv[j][1];
            }
        }
        float inv = 1.f / (s + 1e-16f);
        float2 bv = *(const float2*)(bias + lane * 2);
        acc.x = acc.x * inv + bv.x; acc.y = acc.y * inv + bv.y;
        if (RELU) { acc.x = fmaxf(acc.x, 0.f); acc.y = fmaxf(acc.y, 0.f); }
        *(float2*)(out + (size_t)node * C + lane * 2) = acc;
    }
}

extern "C" void kernel_launch(void* const* d_in, const int* in_sizes, int n_in,
                              void* d_out, int out_size, void* d_ws, size_t ws_size,
                              hipStream_t stream) {
    const float* x     = (const float*)d_in[0];
    const int*   edge  = (const int*)d_in[1];
    const int*   src   = edge;
    const int*   dst   = edge + N_EDGES;
    const float* W1s   = (const float*)d_in[2];
    const float* W1d   = (const float*)d_in[3];
    const float* att1s = (const float*)d_in[4];
    const float* att1d = (const float*)d_in[5];
    const float* b1    = (const float*)d_in[6];
    const float* W2s   = (const float*)d_in[7];
    const float* W2d   = (const float*)d_in[8];
    const float* att2s = (const float*)d_in[9];
    const float* att2d = (const float*)d_in[10];
    const float* b2    = (const float*)d_in[11];
    float* out = (float*)d_out;

    // -------- workspace layout (r10 form; act2 region reinterpreted as hi|lo) --------
    float* ws    = (float*)d_ws;
    half_t* h1   = (half_t*)ws;                        // N*256 halves (region N*256 floats)
    unsigned short* act2hi = (unsigned short*)(ws + (size_t)N_NODES * HID);   // N*256 ushort
    unsigned short* act2lo = act2hi + (size_t)N_NODES * HID;                  // N*256 ushort
    float* a_s   = ws + 2 * (size_t)N_NODES * HID;     // N
    float* a_d   = a_s + N_NODES;                      // N
    float* vbuf  = a_d + N_NODES;                      // 4*256
    int* ibase      = (int*)(vbuf + 4 * HID);
    int* src_sorted = ibase;                           // E
    int* rank       = src_sorted + N_EDGES;            // E
    int* counts     = rank + N_EDGES;                  // N
    int* offsets    = counts + N_NODES;                // N+1
    int* blockSums  = offsets + N_NODES + 1;           // SCAN_NB
    unsigned short* wp1h = (unsigned short*)(((uintptr_t)(blockSums + SCAN_NB) + 15) & ~(uintptr_t)15);
    unsigned short* wp1l = wp1h + PACK1_T * 8;
    unsigned short* wp2h = wp1l + PACK1_T * 8;
    unsigned short* wp2l = wp2h + PACK2_T * 8;
    float* v1s = vbuf, *v1d = vbuf + HID, *v2s = vbuf + 2 * HID, *v2d = vbuf + 3 * HID;
    half_t* h2 = h1;

    const int edgeBlocks = (N_EDGES + 255) / 256;
    const int waveBlocksN = (N_NODES + 3) / 4;
    const int gemmBlocks = (N_NODES + 127) / 128;      // 391

    // -------- CSR build (atomic only in hist; scatter is rank-addressed) --------
    hipMemsetAsync(counts, 0, N_NODES * sizeof(int), stream);
    hist_rank_kernel<<<edgeBlocks, 256, 0, stream>>>(dst, counts, rank);
    block_scan_kernel<<<SCAN_NB, 256, 0, stream>>>(counts, offsets, blockSums, N_NODES);
    add_offsets_kernel<<<SCAN_NB, 256, 0, stream>>>(offsets, blockSums, N_NODES);
    scatter_kernel<<<edgeBlocks, 256, 0, stream>>>(src, dst, offsets, rank, src_sorted);

    // -------- v vectors + packed B (both layers) --------
    compute_v_all_kernel<<<dim3(HID, 4), 64, 0, stream>>>(
        W1s, att1s, W1d, att1d, W2s, att2s, W2d, att2d, v1s, v1d, v2s, v2d);
    pack_all_kernel<<<(PACK1_T + PACK2_T + 255) / 256, 256, 0, stream>>>(
        W1s, v1s, v1d, W2s, v2s, v2d, wp1h, wp1l, wp2h, wp2l);

    // -------- layer 1 (fp32 A, in-kernel convert — r10-proven) --------
    mfma_gemm_a_kernel<HID, false><<<dim3(gemmBlocks, 2), 256, 0, stream>>>(
        x, nullptr, nullptr, wp1h, wp1l, h1, a_s, a_d, N_NODES);
    fused_aggregate_kernel<HID, true, true><<<waveBlocksN, 256, 0, stream>>>(
        offsets, src_sorted, a_s, a_d, h1, b1, nullptr, act2hi, act2lo);

    // -------- layer 2 (pre-split A from agg1's OSPLIT — zero-cost split) --------
    mfma_gemm_a_kernel<OUT_C, true><<<dim3(gemmBlocks, 1), 256, 0, stream>>>(
        nullptr, act2hi, act2lo, wp2h, wp2l, h2, a_s, a_d, N_NODES);
    fused_aggregate_kernel<OUT_C, false, false><<<waveBlocksN, 256, 0, stream>>>(
        offsets, src_sorted, a_s, a_d, h2, b2, out, nullptr, nullptr);
}

// Round 14
// 304.879 us; speedup vs baseline: 1.2813x; 1.0479x over previous
//
#include <hip/hip_runtime.h>
#include <math.h>

#define N_NODES 50000
#define N_EDGES 800000
#define HID 256
#define OUT_C 128
#define NEG_SLOPE 0.2f
#define SCAN_NB ((N_NODES + 255) / 256)   // 196

typedef __attribute__((ext_vector_type(8))) short bf16x8;   // 8 bf16 (4 VGPRs)
typedef __attribute__((ext_vector_type(4))) float f32x4;    // MFMA C/D
typedef _Float16 half_t;
typedef __attribute__((ext_vector_type(4))) _Float16 half4;
typedef __attribute__((ext_vector_type(2))) _Float16 half2t;

__device__ inline unsigned short bf16_rne(float x) {
    unsigned u = __float_as_uint(x);
    return (unsigned short)((u + 0x7fffu + ((u >> 16) & 1u)) >> 16);
}

// async global->LDS, 16B per lane (wave-uniform LDS base + lane*16 by HW)
__device__ __forceinline__ void async_copy16(const void* g, void* l) {
    __builtin_amdgcn_global_load_lds(
        (const __attribute__((address_space(1))) unsigned int*)g,
        (__attribute__((address_space(3))) unsigned int*)l, 16, 0, 0);
}

// ---------------- CSR build: hist (+rank), scan ----------------

__global__ __launch_bounds__(256) void hist_rank_kernel(
    const int* __restrict__ dst, int* __restrict__ counts, int* __restrict__ rank) {
    int e = blockIdx.x * 256 + threadIdx.x;
    if (e < N_EDGES) rank[e] = atomicAdd(&counts[dst[e]], 1);
}

__global__ __launch_bounds__(256) void block_scan_kernel(
    const int* __restrict__ counts, int* __restrict__ excl,
    int* __restrict__ blockSums, int n) {
    __shared__ int waveSums[4];
    int i = blockIdx.x * 256 + threadIdx.x;
    int lane = threadIdx.x & 63;
    int wv = threadIdx.x >> 6;
    int c = (i < n) ? counts[i] : 0;
    int v = c;
    #pragma unroll
    for (int off = 1; off < 64; off <<= 1) {
        int t = __shfl_up(v, off);
        if (lane >= off) v += t;
    }
    if (lane == 63) waveSums[wv] = v;
    __syncthreads();
    int waveOff = 0;
    #pragma unroll
    for (int w = 0; w < 4; w++)
        if (w < wv) waveOff += waveSums[w];
    if (i < n) excl[i] = waveOff + v - c;
    if (threadIdx.x == 255) blockSums[blockIdx.x] = waveOff + v;
}

__global__ __launch_bounds__(256) void add_offsets_kernel(
    int* __restrict__ excl, const int* __restrict__ blockSums, int n) {
    __shared__ int lds[4];
    int tid = threadIdx.x;
    int partial = 0;
    for (int j = tid; j < (int)blockIdx.x; j += 256) partial += blockSums[j];
    #pragma unroll
    for (int off = 32; off > 0; off >>= 1) partial += __shfl_down(partial, off);
    if ((tid & 63) == 0) lds[tid >> 6] = partial;
    __syncthreads();
    int prefix = lds[0] + lds[1] + lds[2] + lds[3];
    int i = blockIdx.x * 256 + tid;
    if (i < n) excl[i] += prefix;
    if (i == 0) excl[n] = N_EDGES;
}

// ---------------- merged prep: scatter + pack W + compute_v->pack slots ----------------
// Three independent wave-parallel job types in one launch (saves 2 dispatch
// gaps; scatter's random writes overlap pack/v compute). pack blocks skip the
// v-tile; compute_v waves (one per k) do the wave-parallel dot-product then
// write their 16 v-tile slots directly. No serial loops (r8 lesson), no
// cross-block dependencies (v slots disjoint from pack slots).

#define PACK1_T (8 * 17 * 64)   // 8704
#define PACK2_T (8 * 9 * 64)    // 4608
#define EDGE_BLOCKS ((N_EDGES + 255) / 256)               // 3125
#define PACK_BLOCKS ((PACK1_T + PACK2_T + 255) / 256)     // 52
#define V_BLOCKS 128                                      // 2 layers x 256 k / 4 waves

__global__ __launch_bounds__(256) void prep_kernel(
    const int* __restrict__ src, const int* __restrict__ dst,
    const int* __restrict__ offsets, const int* __restrict__ rank,
    int* __restrict__ src_sorted,
    const float* __restrict__ W1s, const float* __restrict__ att1s,
    const float* __restrict__ W1d, const float* __restrict__ att1d,
    const float* __restrict__ W2s, const float* __restrict__ att2s,
    const float* __restrict__ W2d, const float* __restrict__ att2d,
    unsigned short* __restrict__ hi1, unsigned short* __restrict__ lo1,
    unsigned short* __restrict__ hi2, unsigned short* __restrict__ lo2) {
    if (blockIdx.x < EDGE_BLOCKS) {
        int e = blockIdx.x * 256 + threadIdx.x;
        if (e < N_EDGES)
            src_sorted[offsets[dst[e]] + rank[e]] = src[e];
        return;
    }
    if (blockIdx.x < EDGE_BLOCKS + PACK_BLOCKS) {
        int t = (blockIdx.x - EDGE_BLOCKS) * 256 + threadIdx.x;
        const float *W; unsigned short *hi, *lo; int cout, NTL, tt;
        if (t < PACK1_T)            { tt = t;           W = W1s; hi = hi1; lo = lo1; cout = HID;  NTL = 17; }
        else if (t < PACK1_T + PACK2_T) { tt = t - PACK1_T; W = W2s; hi = hi2; lo = lo2; cout = OUT_C; NTL = 9; }
        else return;
        int lane = tt & 63;
        int tile = (tt >> 6) % NTL;
        if (tile == NTL - 1) return;           // v-tile written by v-waves below
        int ks = tt / (64 * NTL);
        int m = lane & 15;
        int kbase = ks * 32 + (lane >> 4) * 8;
        #pragma unroll
        for (int j = 0; j < 8; j++) {
            float val = W[(size_t)(kbase + j) * cout + tile * 16 + m];
            unsigned short h = bf16_rne(val);
            hi[tt * 8 + j] = h;
            lo[tt * 8 + j] = bf16_rne(val - __uint_as_float((unsigned)h << 16));
        }
        return;
    }
    // ---- compute_v: one wave per k per layer, wave-parallel reduction ----
    int vb = blockIdx.x - EDGE_BLOCKS - PACK_BLOCKS;    // [0, 128)
    int layer = vb >> 6;                                // 0: layer1, 1: layer2
    int wave = threadIdx.x >> 6, lane = threadIdx.x & 63;
    int k = (vb & 63) * 4 + wave;                       // [0, 256)
    const float *Ws, *Wd, *as_, *ad_; unsigned short *hi, *lo; int cout, NTL;
    if (layer == 0) { Ws = W1s; Wd = W1d; as_ = att1s; ad_ = att1d; hi = hi1; lo = lo1; cout = HID;  NTL = 17; }
    else            { Ws = W2s; Wd = W2d; as_ = att2s; ad_ = att2d; hi = hi2; lo = lo2; cout = OUT_C; NTL = 9; }
    float vs = 0.f, vd = 0.f;
    for (int j = lane; j < cout; j += 64) {
        vs += Ws[(size_t)k * cout + j] * as_[j];
        vd += Wd[(size_t)k * cout + j] * ad_[j];
    }
    #pragma unroll
    for (int off = 32; off > 0; off >>= 1) {
        vs += __shfl_down(vs, off);
        vd += __shfl_down(vd, off);
    }
    vs = __shfl(vs, 0);
    vd = __shfl(vd, 0);
    int ks = k >> 5, quad = (k >> 3) & 3, j = k & 7;
    if (lane < 32) {
        int m = lane & 15;
        int tt = ks * 64 * NTL + (NTL - 1) * 64 + quad * 16 + m;
        float val = (m == 0) ? vs : (m == 1) ? vd : 0.f;
        unsigned short h = bf16_rne(val);
        if (lane < 16) hi[tt * 8 + j] = h;
        else           lo[tt * 8 + j] = bf16_rne(val - __uint_as_float((unsigned)h << 16));
    }
}

// ---------------- MFMA GEMM (+ logits): dbuf LDS B, RG-parameterized tile ----------------
// GEMM1: RG=2 (128 rows/block), 2-pass (grid 391x2 = 782 blocks) -- r10-proven.
// GEMM2: RG=1 (64 rows/block), 1-pass grid 782 -- fixes its 391-block
// occupancy starvation (1.5 blocks/CU, the r9 failure mode).
// ASPLIT: layer 2 reads A as pre-split hi/lo bf16 (agg1's OSPLIT, zero cost).

template <int COUT, int NT, int RG, bool WRITE_A, bool ASPLIT>
__device__ __forceinline__ void gemm_body(
    const float* __restrict__ A,
    const unsigned short* __restrict__ Ahi, const unsigned short* __restrict__ Alo,
    const unsigned short* __restrict__ Bhi, const unsigned short* __restrict__ Blo,
    half_t* __restrict__ H,
    float* __restrict__ a_s, float* __restrict__ a_d, int M, int tile0,
    short* sBh, short* sBl) {
    const int NTL = COUT / 16 + 1;
    int wave = threadIdx.x >> 6, lane = threadIdx.x & 63;
    int m = lane & 15, quad = lane >> 4;
    int row0 = blockIdx.x * (RG * 64) + wave * (RG * 16);
    f32x4 acc[RG][NT];
    #pragma unroll
    for (int rg = 0; rg < RG; rg++)
        #pragma unroll
        for (int nt = 0; nt < NT; nt++)
            acc[rg][nt] = (f32x4){0.f, 0.f, 0.f, 0.f};

    const float* arow[RG];
    const unsigned short* arh[RG];
    const unsigned short* arl[RG];
    #pragma unroll
    for (int rg = 0; rg < RG; rg++) {
        int r = row0 + rg * 16 + m;
        if (r >= M) r = M - 1;          // clamp: pad rows never stored
        if (ASPLIT) {
            arh[rg] = Ahi + (size_t)r * HID;
            arl[rg] = Alo + (size_t)r * HID;
        } else {
            arow[rg] = A + (size_t)r * HID;
        }
    }

    // stage K-slice ks into buffer b (hi+lo: 2*NT 1KB units, round-robin waves)
    auto STAGE = [&](int ks, int b) {
        for (int u = wave; u < 2 * NT; u += 4) {
            int nt = (u < NT) ? u : u - NT;
            int tile = (WRITE_A && nt == NT - 1) ? (COUT / 16) : (tile0 + nt);
            size_t goff = ((size_t)(ks * NTL + tile) * 64 + lane) * 8;
            if (u < NT) async_copy16(Bhi + goff, sBh + b * NT * 512 + nt * 512);
            else        async_copy16(Blo + goff, sBl + b * NT * 512 + nt * 512);
        }
    };

    STAGE(0, 0);
    __syncthreads();                     // drain prologue stage
    int cur = 0;
    for (int ks = 0; ks < 8; ks++) {
        if (ks < 7) STAGE(ks + 1, cur ^ 1);  // prefetch overlaps compute below

        bf16x8 ah[RG], al[RG];
        #pragma unroll
        for (int rg = 0; rg < RG; rg++) {
            if (ASPLIT) {
                ah[rg] = *(const bf16x8*)(arh[rg] + ks * 32 + quad * 8);
                al[rg] = *(const bf16x8*)(arl[rg] + ks * 32 + quad * 8);
            } else {
                const float* ap = arow[rg] + ks * 32 + quad * 8;
                float4 v0 = *(const float4*)ap;
                float4 v1 = *(const float4*)(ap + 4);
                float av[8] = {v0.x, v0.y, v0.z, v0.w, v1.x, v1.y, v1.z, v1.w};
                #pragma unroll
                for (int j = 0; j < 8; j++) {
                    unsigned short h = bf16_rne(av[j]);
                    float hf = __uint_as_float((unsigned)h << 16);
                    ah[rg][j] = (short)h;
                    al[rg][j] = (short)bf16_rne(av[j] - hf);
                }
            }
        }
        #pragma unroll
        for (int nt = 0; nt < NT; nt++) {
            bf16x8 bh = *(const bf16x8*)(sBh + cur * NT * 512 + nt * 512 + lane * 8);
            bf16x8 bl = *(const bf16x8*)(sBl + cur * NT * 512 + nt * 512 + lane * 8);
            #pragma unroll
            for (int rg = 0; rg < RG; rg++) {
                acc[rg][nt] = __builtin_amdgcn_mfma_f32_16x16x32_bf16(ah[rg], bh, acc[rg][nt], 0, 0, 0);
                acc[rg][nt] = __builtin_amdgcn_mfma_f32_16x16x32_bf16(ah[rg], bl, acc[rg][nt], 0, 0, 0);
                acc[rg][nt] = __builtin_amdgcn_mfma_f32_16x16x32_bf16(al[rg], bh, acc[rg][nt], 0, 0, 0);
            }
        }
        __syncthreads();                 // read-safety + drains prefetch
        cur ^= 1;
    }
    // C/D layout: col = lane&15, row = quad*4 + reg  [m89-verified]
    const int NW = WRITE_A ? NT - 1 : NT;
    #pragma unroll
    for (int rg = 0; rg < RG; rg++)
        #pragma unroll
        for (int nt = 0; nt < NW; nt++)
            #pragma unroll
            for (int r = 0; r < 4; r++) {
                int row = row0 + rg * 16 + quad * 4 + r;
                if (row < M)
                    H[(size_t)row * COUT + (tile0 + nt) * 16 + m] = (half_t)acc[rg][nt][r];
            }
    if (WRITE_A) {
        #pragma unroll
        for (int rg = 0; rg < RG; rg++)
            #pragma unroll
            for (int r = 0; r < 4; r++) {
                int row = row0 + rg * 16 + quad * 4 + r;
                if (row < M) {
                    if (m == 0) a_s[row] = acc[rg][NT - 1][r];
                    else if (m == 1) a_d[row] = acc[rg][NT - 1][r];
                }
            }
    }
}

template <int COUT, int RG, bool ASPLIT>
__global__ __launch_bounds__(256) void mfma_gemm_a_kernel(
    const float* __restrict__ A,
    const unsigned short* __restrict__ Ahi, const unsigned short* __restrict__ Alo,
    const unsigned short* __restrict__ Bhi, const unsigned short* __restrict__ Blo,
    half_t* __restrict__ H,
    float* __restrict__ a_s, float* __restrict__ a_d, int M) {
    __shared__ short sBh[2 * 9 * 512];   // 18KB (dbuf)
    __shared__ short sBl[2 * 9 * 512];   // 18KB (dbuf) -> 36KB total
    if (blockIdx.y == 0)
        gemm_body<COUT, 9, RG, true, ASPLIT>(A, Ahi, Alo, Bhi, Blo, H, a_s, a_d, M, 0, sBh, sBl);
    else
        gemm_body<COUT, 8, RG, false, ASPLIT>(A, Ahi, Alo, Bhi, Blo, H, a_s, a_d, M, 8, sBh, sBl);
}

// ---------------- fused aggregation: one wave per dst node (at fabric ceiling) ----------------
// OSPLIT: layer-1 writes act2 as hi/lo bf16 pairs (same byte count as fp32,
// same rounding GEMM2 would apply) so GEMM2 gets pre-split A for free.

template <int C, bool RELU, bool OSPLIT>
__global__ __launch_bounds__(256) void fused_aggregate_kernel(
    const int* __restrict__ offsets, const int* __restrict__ src_sorted,
    const float* __restrict__ a_src, const float* __restrict__ a_dst,
    const half_t* __restrict__ h, const float* __restrict__ bias,
    float* __restrict__ out,
    unsigned short* __restrict__ outhi, unsigned short* __restrict__ outlo) {
    constexpr int CH = 8;
    int node = (int)((blockIdx.x * 256u + threadIdx.x) >> 6);
    int lane = threadIdx.x & 63;
    if (node >= N_NODES) return;
    int beg = offsets[node], end = offsets[node + 1];
    float ad = a_dst[node];
    float s = 0.f;

    if (C == 256) {
        float4 acc = make_float4(0.f, 0.f, 0.f, 0.f);
        for (int base = beg; base < end; base += CH) {
            int cnt = end - base; if (cnt > CH) cnt = CH;
            int idx[CH];
            #pragma unroll
            for (int j = 0; j < CH; j++)
                idx[j] = src_sorted[(j < cnt) ? base + j : base];
            half4 hv[CH];
            #pragma unroll
            for (int j = 0; j < CH; j++)   // 8 independent 512B row gathers in flight
                hv[j] = *(const half4*)(h + ((unsigned)idx[j] * C + lane * 4));
            float w[CH];
            #pragma unroll
            for (int j = 0; j < CH; j++) {
                float l = a_src[idx[j]] + ad;
                l = fmaxf(l, l * NEG_SLOPE);
                w[j] = (j < cnt) ? __expf(l) : 0.f;
                s += w[j];
            }
            #pragma unroll
            for (int j = 0; j < CH; j++) {
                acc.x += w[j] * (float)hv[j][0]; acc.y += w[j] * (float)hv[j][1];
                acc.z += w[j] * (float)hv[j][2]; acc.w += w[j] * (float)hv[j][3];
            }
        }
        float inv = 1.f / (s + 1e-16f);
        float4 bv = *(const float4*)(bias + lane * 4);
        acc.x = acc.x * inv + bv.x; acc.y = acc.y * inv + bv.y;
        acc.z = acc.z * inv + bv.z; acc.w = acc.w * inv + bv.w;
        if (RELU) {
            acc.x = fmaxf(acc.x, 0.f); acc.y = fmaxf(acc.y, 0.f);
            acc.z = fmaxf(acc.z, 0.f); acc.w = fmaxf(acc.w, 0.f);
        }
        if (OSPLIT) {
            float o[4] = {acc.x, acc.y, acc.z, acc.w};
            ushort4 h4, l4;
            unsigned short* hp = (unsigned short*)&h4;
            unsigned short* lp = (unsigned short*)&l4;
            #pragma unroll
            for (int j = 0; j < 4; j++) {
                unsigned short hh = bf16_rne(o[j]);
                hp[j] = hh;
                lp[j] = bf16_rne(o[j] - __uint_as_float((unsigned)hh << 16));
            }
            *(ushort4*)(outhi + (size_t)node * C + lane * 4) = h4;
            *(ushort4*)(outlo + (size_t)node * C + lane * 4) = l4;
        } else {
            *(float4*)(out + (size_t)node * C + lane * 4) = acc;
        }
    } else {
        float2 acc = make_float2(0.f, 0.f);
        for (int base = beg; base < end; base += CH) {
            int cnt = end - base; if (cnt > CH) cnt = CH;
            int idx[CH];
            #pragma unroll
            for (int j = 0; j < CH; j++)
                idx[j] = src_sorted[(j < cnt) ? base + j : base];
            half2t hv[CH];
            #pragma unroll
            for (int j = 0; j < CH; j++)
                hv[j] = *(const half2t*)(h + ((unsigned)idx[j] * C + lane * 2));
            float w[CH];
            #pragma unroll
            for (int j = 0; j < CH; j++) {
                float l = a_src[idx[j]] + ad;
                l = fmaxf(l, l * NEG_SLOPE);
                w[j] = (j < cnt) ? __expf(l) : 0.f;
                s += w[j];
            }
            #pragma unroll
            for (int j = 0; j < CH; j++) {
                acc.x += w[j] * (float)hv[j][0]; acc.y += w[j] * (float)hv[j][1];
            }
        }
        float inv = 1.f / (s + 1e-16f);
        float2 bv = *(const float2*)(bias + lane * 2);
        acc.x = acc.x * inv + bv.x; acc.y = acc.y * inv + bv.y;
        if (RELU) { acc.x = fmaxf(acc.x, 0.f); acc.y = fmaxf(acc.y, 0.f); }
        *(float2*)(out + (size_t)node * C + lane * 2) = acc;
    }
}

extern "C" void kernel_launch(void* const* d_in, const int* in_sizes, int n_in,
                              void* d_out, int out_size, void* d_ws, size_t ws_size,
                              hipStream_t stream) {
    const float* x     = (const float*)d_in[0];
    const int*   edge  = (const int*)d_in[1];
    const int*   src   = edge;
    const int*   dst   = edge + N_EDGES;
    const float* W1s   = (const float*)d_in[2];
    const float* W1d   = (const float*)d_in[3];
    const float* att1s = (const float*)d_in[4];
    const float* att1d = (const float*)d_in[5];
    const float* b1    = (const float*)d_in[6];
    const float* W2s   = (const float*)d_in[7];
    const float* W2d   = (const float*)d_in[8];
    const float* att2s = (const float*)d_in[9];
    const float* att2d = (const float*)d_in[10];
    const float* b2    = (const float*)d_in[11];
    float* out = (float*)d_out;

    // -------- workspace layout (r13 form) --------
    float* ws    = (float*)d_ws;
    half_t* h1   = (half_t*)ws;                        // N*256 halves (region N*256 floats)
    unsigned short* act2hi = (unsigned short*)(ws + (size_t)N_NODES * HID);   // N*256 ushort
    unsigned short* act2lo = act2hi + (size_t)N_NODES * HID;                  // N*256 ushort
    float* a_s   = ws + 2 * (size_t)N_NODES * HID;     // N
    float* a_d   = a_s + N_NODES;                      // N
    int* ibase      = (int*)(a_d + N_NODES);
    int* src_sorted = ibase;                           // E
    int* rank       = src_sorted + N_EDGES;            // E
    int* counts     = rank + N_EDGES;                  // N
    int* offsets    = counts + N_NODES;                // N+1
    int* blockSums  = offsets + N_NODES + 1;           // SCAN_NB
    unsigned short* wp1h = (unsigned short*)(((uintptr_t)(blockSums + SCAN_NB) + 15) & ~(uintptr_t)15);
    unsigned short* wp1l = wp1h + PACK1_T * 8;
    unsigned short* wp2h = wp1l + PACK1_T * 8;
    unsigned short* wp2l = wp2h + PACK2_T * 8;
    half_t* h2 = h1;

    const int waveBlocksN = (N_NODES + 3) / 4;
    const int gemmBlocks1 = (N_NODES + 127) / 128;     // 391 (RG=2)
    const int gemmBlocks2 = (N_NODES + 63) / 64;       // 782 (RG=1)

    // -------- CSR build --------
    hipMemsetAsync(counts, 0, N_NODES * sizeof(int), stream);
    hist_rank_kernel<<<EDGE_BLOCKS, 256, 0, stream>>>(dst, counts, rank);
    block_scan_kernel<<<SCAN_NB, 256, 0, stream>>>(counts, offsets, blockSums, N_NODES);
    add_offsets_kernel<<<SCAN_NB, 256, 0, stream>>>(offsets, blockSums, N_NODES);

    // -------- scatter + pack + v (one launch, independent job types) --------
    prep_kernel<<<EDGE_BLOCKS + PACK_BLOCKS + V_BLOCKS, 256, 0, stream>>>(
        src, dst, offsets, rank, src_sorted,
        W1s, att1s, W1d, att1d, W2s, att2s, W2d, att2d,
        wp1h, wp1l, wp2h, wp2l);

    // -------- layer 1 (fp32 A, in-kernel convert; RG=2 2-pass, 782 blocks) --------
    mfma_gemm_a_kernel<HID, 2, false><<<dim3(gemmBlocks1, 2), 256, 0, stream>>>(
        x, nullptr, nullptr, wp1h, wp1l, h1, a_s, a_d, N_NODES);
    fused_aggregate_kernel<HID, true, true><<<waveBlocksN, 256, 0, stream>>>(
        offsets, src_sorted, a_s, a_d, h1, b1, nullptr, act2hi, act2lo);

    // -------- layer 2 (pre-split A; RG=1 1-pass, 782 blocks) --------
    mfma_gemm_a_kernel<OUT_C, 1, true><<<dim3(gemmBlocks2, 1), 256, 0, stream>>>(
        nullptr, act2hi, act2lo, wp2h, wp2l, h2, a_s, a_d, N_NODES);
    fused_aggregate_kernel<OUT_C, false, false><<<waveBlocksN, 256, 0, stream>>>(
        offsets, src_sorted, a_s, a_d, h2, b2, out, nullptr, nullptr);
}